// Round 11
// baseline (753.529 us; speedup 1.0000x reference)
//
#include <hip/hip_runtime.h>

#define C 64
#define K 1024
#define HW 4096
#define N_TOTAL 131072   // 32*64*64
#define OUT0 8388608     // 32*64*64*64 (z_q_out elements)
#define MT 128           // n-rows per block
#define KT2 64           // codes per MFMA k-tile
#define NT2 (K / KT2)    // 16

#define GAP_THR 2.5e-4f  // certainty margin (>=4x worst-case approx error)
#define CHK_THR 1e-4f    // layout self-check threshold

// d_ws float layout (main path)
#define WS_EK        0                    // 1024 f
#define WS_ROWLOSS   1024                 // 131072 f
#define WS_BESTI     132096               // 131072 int
#define WS_ULIST     263168               // 131072 int
#define WS_UCOUNT    394240               // 16 int
#define WS_EBF       394256               // 65536 shorts = 32768 f
#define WS_NEED2     (394256 + 32768)

typedef unsigned int u32;
typedef unsigned long long u64;
typedef __attribute__((ext_vector_type(8))) short short8;
typedef __attribute__((ext_vector_type(4))) float f32x4;
typedef const __attribute__((address_space(1))) void* gas_ptr;
typedef __attribute__((address_space(3))) void* las_ptr;

// monotone float map + index pack: lexicographic min == (min d, then min k)
__device__ __forceinline__ u64 packdk(float d, int k) {
    u32 b = __float_as_uint(d);
    u32 m = b ^ ((u32)((int)b >> 31) | 0x80000000u);
    return ((u64)m << 32) | (u32)k;
}
// bf16 round-to-nearest-even (bit trick; exact rounding mode irrelevant —
// only the residual bound matters for the split scheme)
__device__ __forceinline__ unsigned short f2bf(float x) {
    u32 u = __float_as_uint(x);
    return (unsigned short)((u + 0x7FFFu + ((u >> 16) & 1u)) >> 16);
}
__device__ __forceinline__ float bf2f(unsigned short h) {
    u32 u = ((u32)h) << 16;
    return __uint_as_float(u);
}

// ---------------------------------------------------------------------------
// Kernel 1: E prep. ek = ||e_k||^2 numpy pairwise-8 (FROZEN, absmax 0.0
// R1-R10) + split-bf16 planes of E packed into swizzled 16B chunks:
// chunk (k, ci) with ci = plane*8 + c/8 stored at slot k*16 + (ci ^ (k&7))
// so a linear global_load_lds copy yields bank-conflict-free B-frag reads.
// Also zeroes the uncertain-row counter (runs before vq_mfma, stream-ordered).
// ---------------------------------------------------------------------------
__global__ __launch_bounds__(256) void eprep2(const float* __restrict__ E,
                                              float* __restrict__ ek,
                                              short* __restrict__ EbfS,
                                              int* __restrict__ ucount) {
#pragma clang fp contract(off)
    if (blockIdx.x == 0 && threadIdx.x == 0) *ucount = 0;
    int k = blockIdx.x * 256 + threadIdx.x;
    const float* e = E + k * C;
    float ev[C];
#pragma unroll
    for (int c4 = 0; c4 < 16; ++c4) {
        float4 v = *(const float4*)(e + c4 * 4);
        ev[c4 * 4 + 0] = v.x; ev[c4 * 4 + 1] = v.y;
        ev[c4 * 4 + 2] = v.z; ev[c4 * 4 + 3] = v.w;
    }
    float r[8];
#pragma unroll
    for (int j = 0; j < 8; ++j) r[j] = ev[j] * ev[j];
#pragma unroll
    for (int i = 8; i < C; i += 8)
#pragma unroll
        for (int j = 0; j < 8; ++j) r[j] += ev[i + j] * ev[i + j];
    ek[k] = ((r[0] + r[1]) + (r[2] + r[3])) + ((r[4] + r[5]) + (r[6] + r[7]));

    unsigned short hi[C], lo[C];
#pragma unroll
    for (int c = 0; c < C; ++c) {
        unsigned short h = f2bf(ev[c]);
        hi[c] = h;
        lo[c] = f2bf(ev[c] - bf2f(h));
    }
#pragma unroll
    for (int ci = 0; ci < 16; ++ci) {
        int p = ci >> 3, c0 = (ci & 7) * 8;
        short8 v;
#pragma unroll
        for (int e2 = 0; e2 < 8; ++e2)
            v[e2] = (short)(p ? lo[c0 + e2] : hi[c0 + e2]);
        int slot = k * 16 + (ci ^ (k & 7));
        *(short8*)&EbfS[slot * 8] = v;
    }
}

// ---------------------------------------------------------------------------
// Kernel 2: MFMA argmin. Block = 128 n-rows x all 1024 codes, 4 waves.
// Phases: (1) stage Zt fp32 [c][n] (coalesced) (2) per-wave exact seq-fma
// check dot + convert Z to split-bf16 A-planes Zb[n][pl][c] (3) k-tiles of
// 64 codes staged via global_load_lds; per 16x16 output tile 6 MFMA
// (2 K-steps x 3 planes: hh, hl, lh) -> S; d_cmp = fmaf(-2,S,ek); per-row
// (d1,k1,d2) with ascending-k strict <. Fragment layouts assumed:
//   A: row=lane&15, k=(lane>>4)*8+e;  B: col=lane&15, k=(lane>>4)*8+e;
//   C/D: col=lane&15, row=(lane>>4)*4+reg  [m89-verified].
// SELF-CHECK: wave compares MFMA S (tile0,cg0,rt0,reg0) vs exact dot; any
// mismatch -> block flag -> all 128 rows routed to exact fallback (fail-safe
// against layout/conversion bugs). Certainty: gap d2-d1 > GAP_THR proves the
// exact numpy argmin == k1 (error bound << GAP_THR); else row -> fallback.
// ---------------------------------------------------------------------------
__global__ __launch_bounds__(256, 2) void vq_mfma(const float* __restrict__ Z,
                                                  const float* __restrict__ Efp,
                                                  const float* __restrict__ ek,
                                                  const short* __restrict__ EbfS,
                                                  int* __restrict__ besti,
                                                  int* __restrict__ ulist,
                                                  int* __restrict__ ucount) {
#pragma clang fp contract(off)
    __shared__ float SA[8192];             // phase1: ZtF [c][128n]; phase3: E-tile (16KB)
    __shared__ unsigned short Zb[16384];   // [128n][pl*64+c] bf16 planes
    __shared__ int flagLds;

    const int t = threadIdx.x;
    const int wave = t >> 6, lane = t & 63;
    const int n0 = blockIdx.x * MT;
    const int b = n0 >> 12;
    const int hw0 = n0 & 4095;
    const float* zbase = Z + b * (C * HW) + hw0;
    if (t == 0) flagLds = 0;

    // ---- phase 1: stage ZtF fp32 (coalesced) ----
#pragma unroll
    for (int r = 0; r < 8; ++r) {
        int idx4 = r * 256 + t;
        int c = idx4 >> 5, n4 = idx4 & 31;
        float4 v = *(const float4*)(zbase + c * HW + n4 * 4);
        *(float4*)(&SA[c * MT + n4 * 4]) = v;
    }
    __syncthreads();

    const int wr = wave * 32;
    // ---- exact check dot: row wr+(lane>>4)*4, code lane&15 (seq fma) ----
    float a_chk = 0.0f;
    {
        int rl = wr + ((lane >> 4) << 2);
        const float* ep = Efp + (lane & 15) * C;
#pragma unroll 4
        for (int c = 0; c < C; ++c)
            a_chk = __builtin_fmaf(SA[c * MT + rl], ep[c], a_chk);
    }
    // ---- convert to split-bf16 A planes: thread (r = t&127, p = t>>7) ----
    {
        int r = t & 127, p = t >> 7;
#pragma unroll
        for (int c8 = 0; c8 < 8; ++c8) {
            short8 v;
#pragma unroll
            for (int e2 = 0; e2 < 8; ++e2) {
                float z = SA[(c8 * 8 + e2) * MT + r];
                unsigned short h = f2bf(z);
                v[e2] = (short)(p ? f2bf(z - bf2f(h)) : h);
            }
            *(short8*)&Zb[r * 128 + p * 64 + c8 * 8] = v;
        }
    }
    __syncthreads();   // ZtF dead; Zb ready

    // ---- A fragments (persist whole kernel): [rt][ks][plane] ----
    short8 af[2][2][2];
#pragma unroll
    for (int rt = 0; rt < 2; ++rt)
#pragma unroll
        for (int ks = 0; ks < 2; ++ks)
#pragma unroll
            for (int p = 0; p < 2; ++p)
                af[rt][ks][p] = *(const short8*)&Zb[(wr + rt * 16 + (lane & 15)) * 128
                                                   + p * 64 + ks * 32 + ((lane >> 4) << 3)];

    // ---- issue E-tile 0 via DMA (linear copy of swizzled chunks) ----
#pragma unroll
    for (int p2 = 0; p2 < 4; ++p2) {
        int q = wave * 4 + p2;
        const char* gsrc = (const char*)EbfS + q * 1024 + lane * 16;
        __builtin_amdgcn_global_load_lds((gas_ptr)gsrc,
                                         (las_ptr)((char*)SA + q * 1024), 16, 0, 0);
    }
    __syncthreads();

    float d1f[8], d2f[8];
    int k1[8];
#pragma unroll
    for (int s = 0; s < 8; ++s) { d1f[s] = __builtin_inff(); d2f[s] = __builtin_inff(); k1[s] = 0; }

#pragma unroll 1
    for (int tau = 0; tau < NT2; ++tau) {
#pragma unroll 1
        for (int cg = 0; cg < 4; ++cg) {
            int kl = cg * 16 + (lane & 15);
            int kg = tau * KT2 + kl;
            float ekv = ek[kg];
            short8 bf_[2][2];
#pragma unroll
            for (int ks = 0; ks < 2; ++ks)
#pragma unroll
                for (int p = 0; p < 2; ++p) {
                    int ci = p * 8 + ks * 4 + (lane >> 4);
                    int sca = kl * 16 + (ci ^ (kl & 7));
                    bf_[ks][p] = *(const short8*)((const char*)SA + sca * 16);
                }
#pragma unroll
            for (int rt = 0; rt < 2; ++rt) {
                f32x4 acc = {0.0f, 0.0f, 0.0f, 0.0f};
                acc = __builtin_amdgcn_mfma_f32_16x16x32_bf16(af[rt][0][0], bf_[0][0], acc, 0, 0, 0);
                acc = __builtin_amdgcn_mfma_f32_16x16x32_bf16(af[rt][0][0], bf_[0][1], acc, 0, 0, 0);
                acc = __builtin_amdgcn_mfma_f32_16x16x32_bf16(af[rt][0][1], bf_[0][0], acc, 0, 0, 0);
                acc = __builtin_amdgcn_mfma_f32_16x16x32_bf16(af[rt][1][0], bf_[1][0], acc, 0, 0, 0);
                acc = __builtin_amdgcn_mfma_f32_16x16x32_bf16(af[rt][1][0], bf_[1][1], acc, 0, 0, 0);
                acc = __builtin_amdgcn_mfma_f32_16x16x32_bf16(af[rt][1][1], bf_[1][0], acc, 0, 0, 0);
                if (tau == 0 && cg == 0 && rt == 0) {
                    if (__builtin_fabsf(acc[0] - a_chk) > CHK_THR) flagLds = 1;
                }
#pragma unroll
                for (int j = 0; j < 4; ++j) {
                    float d = __builtin_fmaf(-2.0f, acc[j], ekv);
                    int s = rt * 4 + j;
                    if (d < d1f[s]) { d2f[s] = d1f[s]; d1f[s] = d; k1[s] = kg; }
                    else if (d < d2f[s]) { d2f[s] = d; }
                }
            }
        }
        __syncthreads();   // all waves done reading E-tile
        if (tau + 1 < NT2) {
#pragma unroll
            for (int p2 = 0; p2 < 4; ++p2) {
                int q = wave * 4 + p2;
                const char* gsrc = (const char*)EbfS + (tau + 1) * 16384 + q * 1024 + lane * 16;
                __builtin_amdgcn_global_load_lds((gas_ptr)gsrc,
                                                 (las_ptr)((char*)SA + q * 1024), 16, 0, 0);
            }
        }
        __syncthreads();   // vmcnt drain -> tile ready
    }

    // ---- merge (d1,k1,d2) across the 16 lanes sharing each row group ----
#pragma unroll
    for (int s = 0; s < 8; ++s) {
        u64 pk = packdk(d1f[s], k1[s]);
        float d1 = d1f[s], d2 = d2f[s];
#pragma unroll
        for (int m = 1; m <= 8; m <<= 1) {
            u64 po = __shfl_xor(pk, m, 64);
            float d1o = __shfl_xor(d1, m, 64);
            float d2o = __shfl_xor(d2, m, 64);
            d2 = fminf(fminf(d2, d2o), fmaxf(d1, d1o));
            d1 = fminf(d1, d1o);
            pk = po < pk ? po : pk;
        }
        d1f[s] = d1; d2f[s] = d2; k1[s] = (int)(pk & 0xFFFFFFFFull);
    }
    int flg = flagLds;
    if ((lane & 15) == 0) {
#pragma unroll
        for (int s = 0; s < 8; ++s) {
            int rt = s >> 2, j = s & 3;
            int n = n0 + wr + rt * 16 + ((lane >> 4) << 2) + j;
            besti[n] = k1[s];
            float gap = d2f[s] - d1f[s];
            if (flg || !(gap > GAP_THR)) {
                int ix = atomicAdd(ucount, 1);
                ulist[ix] = n;
            }
        }
    }
}

// ---------------------------------------------------------------------------
// Kernel 3: exact fallback for uncertain rows — the FROZEN numpy chain
// (pairwise-8 zn, seq-fma dot c=0..63, d = fl(fl(zn+ek)-2a), packdk
// lexicographic min == lowest-k tie-break). One wave per row, grid-stride.
// ---------------------------------------------------------------------------
__global__ __launch_bounds__(256) void vq_fallback(const float* __restrict__ Z,
                                                   const float* __restrict__ E,
                                                   const float* __restrict__ ek,
                                                   const int* __restrict__ ulist,
                                                   const int* __restrict__ ucount,
                                                   int* __restrict__ besti) {
#pragma clang fp contract(off)
    int wid = blockIdx.x * 4 + (threadIdx.x >> 6);
    int lane = threadIdx.x & 63;
    int cnt = *ucount;
    for (int i = wid; i < cnt; i += gridDim.x * 4) {
        int n = ulist[i];
        int b = n >> 12, hw = n & 4095;
        const float* zp = Z + b * (C * HW) + hw;
        float zr[C];
#pragma unroll
        for (int c = 0; c < C; ++c) zr[c] = zp[c * HW];
        float zn;
        {
            float r[8];
#pragma unroll
            for (int j = 0; j < 8; ++j) r[j] = zr[j] * zr[j];
#pragma unroll
            for (int q = 8; q < C; q += 8)
#pragma unroll
                for (int j = 0; j < 8; ++j) r[j] += zr[q + j] * zr[q + j];
            zn = ((r[0] + r[1]) + (r[2] + r[3])) + ((r[4] + r[5]) + (r[6] + r[7]));
        }
        u64 best = ~0ull;
#pragma unroll 1
        for (int j = 0; j < 16; ++j) {
            int k = j * 64 + lane;
            const float* e = E + k * C;
            float a = 0.0f;
#pragma unroll
            for (int c = 0; c < C; ++c) a = __builtin_fmaf(zr[c], e[c], a);
            float A = zn + ek[k];
            float d = A - 2.0f * a;
            u64 p = packdk(d, k);
            if (p < best) best = p;
        }
#pragma unroll
        for (int m = 1; m <= 32; m <<= 1) {
            u64 o = __shfl_xor(best, m, 64);
            best = o < best ? o : best;
        }
        if (lane == 0) besti[n] = (int)(best & 0xFFFFFFFFull);
    }
}

// ---------------------------------------------------------------------------
// Kernel 4: epilogue for ALL rows (FROZEN per-element ops, R3-proven with
// global z reads): z_q straight-through double rounding, index-as-float,
// per-row loss (sequential c adds).
// ---------------------------------------------------------------------------
__global__ __launch_bounds__(256) void vq_epilogue2(const float* __restrict__ Z,
                                                    const float* __restrict__ E,
                                                    const int* __restrict__ besti,
                                                    float* __restrict__ out,
                                                    float* __restrict__ rowloss) {
#pragma clang fp contract(off)
    int n = blockIdx.x * 256 + threadIdx.x;
    int b = n >> 12, hw = n & 4095;
    int best = besti[n];
    const float* zp = Z + b * (C * HW) + hw;
    const float4* eb4 = (const float4*)(E + best * C);
    float* o0 = out + b * (C * HW) + hw;
    float ls = 0.0f;
#pragma unroll
    for (int c4 = 0; c4 < 16; ++c4) {
        float4 e4 = eb4[c4];
        int cb = c4 * 4;
        float z0 = zp[(cb + 0) * HW], z1 = zp[(cb + 1) * HW];
        float z2 = zp[(cb + 2) * HW], z3 = zp[(cb + 3) * HW];
        float f0 = e4.x - z0; o0[(cb + 0) * HW] = z0 + f0; ls += f0 * f0;
        float f1 = e4.y - z1; o0[(cb + 1) * HW] = z1 + f1; ls += f1 * f1;
        float f2 = e4.z - z2; o0[(cb + 2) * HW] = z2 + f2; ls += f2 * f2;
        float f3 = e4.w - z3; o0[(cb + 3) * HW] = z3 + f3; ls += f3 * f3;
    }
    out[OUT0 + n] = (float)best;
    rowloss[n] = ls;
}

// ---------------------------------------------------------------------------
// Kernel 5: deterministic fp64 loss reduction over per-row losses.
// ---------------------------------------------------------------------------
__global__ __launch_bounds__(256) void loss2(const float* __restrict__ rowloss,
                                             float* __restrict__ out) {
    __shared__ double sm[256];
    int t = threadIdx.x;
    double s = 0.0;
    for (int i = t; i < N_TOTAL; i += 256) s += (double)rowloss[i];
    sm[t] = s;
    __syncthreads();
    for (int o = 128; o > 0; o >>= 1) {
        if (t < o) sm[t] += sm[t + o];
        __syncthreads();
    }
    if (t == 0) {
        float m = (float)(sm[0] * (1.0 / 8388608.0));
        out[OUT0 + N_TOTAL] = m + 0.25f * m;
    }
}

// ---------------------------------------------------------------------------
// Small-ws fallback path (R2-proven exact kernels, FROZEN).
// ---------------------------------------------------------------------------
__global__ __launch_bounds__(256) void ek_kernel(const float* __restrict__ E,
                                                 float* __restrict__ ek) {
#pragma clang fp contract(off)
    int k = blockIdx.x * 256 + threadIdx.x;
    if (k >= K) return;
    const float* e = E + k * C;
    float r[8];
#pragma unroll
    for (int j = 0; j < 8; ++j) { float v = e[j]; r[j] = v * v; }
#pragma unroll
    for (int i = 8; i < C; i += 8)
#pragma unroll
        for (int j = 0; j < 8; ++j) { float v = e[i + j]; r[j] += v * v; }
    ek[k] = ((r[0] + r[1]) + (r[2] + r[3])) + ((r[4] + r[5]) + (r[6] + r[7]));
}

__global__ __launch_bounds__(256, 4) void vq_combined(const float* __restrict__ Z,
                                                      const float* __restrict__ E,
                                                      const float* __restrict__ ek,
                                                      float* __restrict__ out,
                                                      float* __restrict__ partials) {
#pragma clang fp contract(off)
    int n = blockIdx.x * 256 + threadIdx.x;
    int b = n >> 12, hw = n & 4095;
    const float* zp = Z + b * (C * HW) + hw;
    float z[C];
#pragma unroll
    for (int c = 0; c < C; ++c) z[c] = zp[c * HW];
    float zn;
    {
        float r[8];
#pragma unroll
        for (int j = 0; j < 8; ++j) r[j] = z[j] * z[j];
#pragma unroll
        for (int i = 8; i < C; i += 8)
#pragma unroll
            for (int j = 0; j < 8; ++j) r[j] += z[i + j] * z[i + j];
        zn = ((r[0] + r[1]) + (r[2] + r[3])) + ((r[4] + r[5]) + (r[6] + r[7]));
    }
    float dmin = __builtin_inff();
    int best = 0;
#pragma unroll 1
    for (int k = 0; k < K; k += 4) {
        const float* e0 = E + k * C;
        float a0 = 0.0f, a1 = 0.0f, a2 = 0.0f, a3 = 0.0f;
#pragma unroll
        for (int c = 0; c < C; ++c) {
            float zc = z[c];
            a0 = __builtin_fmaf(zc, e0[c], a0);
            a1 = __builtin_fmaf(zc, e0[C + c], a1);
            a2 = __builtin_fmaf(zc, e0[2 * C + c], a2);
            a3 = __builtin_fmaf(zc, e0[3 * C + c], a3);
        }
        float A0 = zn + ek[k],     A1 = zn + ek[k + 1];
        float A2 = zn + ek[k + 2], A3 = zn + ek[k + 3];
        float d0 = A0 - 2.0f * a0, d1 = A1 - 2.0f * a1;
        float d2 = A2 - 2.0f * a2, d3 = A3 - 2.0f * a3;
        if (d0 < dmin) { dmin = d0; best = k; }
        if (d1 < dmin) { dmin = d1; best = k + 1; }
        if (d2 < dmin) { dmin = d2; best = k + 2; }
        if (d3 < dmin) { dmin = d3; best = k + 3; }
    }
    const float4* eb4 = (const float4*)(E + best * C);
    float* o0 = out + b * (C * HW) + hw;
    float ls = 0.0f;
#pragma unroll
    for (int c4 = 0; c4 < 16; ++c4) {
        float4 e4 = eb4[c4];
        int cb = c4 * 4;
        float f0 = e4.x - z[cb + 0]; o0[(cb + 0) * HW] = z[cb + 0] + f0; ls += f0 * f0;
        float f1 = e4.y - z[cb + 1]; o0[(cb + 1) * HW] = z[cb + 1] + f1; ls += f1 * f1;
        float f2 = e4.z - z[cb + 2]; o0[(cb + 2) * HW] = z[cb + 2] + f2; ls += f2 * f2;
        float f3 = e4.w - z[cb + 3]; o0[(cb + 3) * HW] = z[cb + 3] + f3; ls += f3 * f3;
    }
    out[OUT0 + n] = (float)best;
#pragma unroll
    for (int off = 32; off > 0; off >>= 1) ls += __shfl_xor(ls, off, 64);
    if ((threadIdx.x & 63) == 0) partials[n >> 6] = ls;
}

__global__ __launch_bounds__(256) void loss_kernel(const float* __restrict__ partials,
                                                   float* __restrict__ out) {
    __shared__ double sm[256];
    int t = threadIdx.x;
    double s = 0.0;
    for (int i = t; i < (N_TOTAL / 64); i += 256) s += (double)partials[i];
    sm[t] = s;
    __syncthreads();
    for (int o = 128; o > 0; o >>= 1) {
        if (t < o) sm[t] += sm[t + o];
        __syncthreads();
    }
    if (t == 0) {
        float m = (float)(sm[0] * (1.0 / 8388608.0));
        out[OUT0 + N_TOTAL] = m + 0.25f * m;
    }
}

extern "C" void kernel_launch(void* const* d_in, const int* in_sizes, int n_in,
                              void* d_out, int out_size, void* d_ws, size_t ws_size,
                              hipStream_t stream) {
    const float* Z = (const float*)d_in[0];
    const float* E = (const float*)d_in[1];
    float* out = (float*)d_out;
    float* ws = (float*)d_ws;
    float* ek = ws + WS_EK;

    if (ws_size >= (size_t)WS_NEED2 * sizeof(float)) {
        float* rowloss = ws + WS_ROWLOSS;
        int* besti  = (int*)(ws + WS_BESTI);
        int* ulist  = (int*)(ws + WS_ULIST);
        int* ucount = (int*)(ws + WS_UCOUNT);
        short* EbfS = (short*)(ws + WS_EBF);

        hipLaunchKernelGGL(eprep2, dim3(K / 256), dim3(256), 0, stream,
                           E, ek, EbfS, ucount);
        hipLaunchKernelGGL(vq_mfma, dim3(N_TOTAL / MT), dim3(256), 0, stream,
                           Z, E, ek, EbfS, besti, ulist, ucount);
        hipLaunchKernelGGL(vq_fallback, dim3(1024), dim3(256), 0, stream,
                           Z, E, ek, ulist, ucount, besti);
        hipLaunchKernelGGL(vq_epilogue2, dim3(N_TOTAL / 256), dim3(256), 0, stream,
                           Z, E, besti, out, rowloss);
        hipLaunchKernelGGL(loss2, dim3(1), dim3(256), 0, stream, rowloss, out);
    } else {
        float* partials = ws + 1024;
        hipLaunchKernelGGL(ek_kernel, dim3(4), dim3(256), 0, stream, E, ek);
        hipLaunchKernelGGL(vq_combined, dim3(N_TOTAL / 256), dim3(256), 0, stream,
                           Z, E, ek, out, partials);
        hipLaunchKernelGGL(loss_kernel, dim3(1), dim3(256), 0, stream, partials, out);
    }
}

// Round 13
// 717.527 us; speedup vs baseline: 1.0502x; 1.0502x over previous
//
#include <hip/hip_runtime.h>

#define C 64
#define K 1024
#define HW 4096
#define N_TOTAL 131072   // 32*64*64
#define OUT0 8388608     // 32*64*64*64 (z_q_out elements)
#define MT 128           // n-rows per block
#define KT2 64           // codes per MFMA k-tile
#define NT2 (K / KT2)    // 16

#define GAP_THR 1.5e-4f  // certainty margin (differential rounding <= ~4e-5)
#define CHK_THR 1e-4f    // layout self-check threshold (|S-a| ~ 1e-6)

// d_ws float layout (main path); rowloss ALIASES ulistA (dead by epilogue).
// R12 BUG FIX: EbfS is 1024 codes x 16 chunks x 16B = 262144 B = 65536
// FLOATS (R12 reserved 32768 -> EbfS overran into Etg rows c<32 -> fallback
// computed garbage dots -> absmax 1020).
#define WS_EK        0                    // 1024 f
#define WS_BESTI     1024                 // 131072 int
#define WS_ULISTA    132096               // 131072 int (flag rows / rowloss)
#define WS_ROWLOSS   132096
#define WS_ULISTB    263168               // 131072 int (gap rows)
#define WS_UCNT      394240               // 16 int
#define WS_EBF       394256               // 131072 shorts = 65536 f
#define WS_ETG       459792               // 65536 f
#define WS_NEED2     525328               // 2.10 MB <= ws (R3-proven >=2.109MB)

typedef unsigned int u32;
typedef unsigned long long u64;
typedef __attribute__((ext_vector_type(8))) short short8;
typedef __attribute__((ext_vector_type(4))) float f32x4;
typedef const __attribute__((address_space(1))) void* gas_ptr;
typedef __attribute__((address_space(3))) void* las_ptr;

__device__ __forceinline__ u64 packdk(float d, int k) {
    u32 b = __float_as_uint(d);
    u32 m = b ^ ((u32)((int)b >> 31) | 0x80000000u);
    return ((u64)m << 32) | (u32)k;
}
__device__ __forceinline__ unsigned short f2bf(float x) {
    u32 u = __float_as_uint(x);
    return (unsigned short)((u + 0x7FFFu + ((u >> 16) & 1u)) >> 16);
}
__device__ __forceinline__ float bf2f(unsigned short h) {
    u32 u = ((u32)h) << 16;
    return __uint_as_float(u);
}

// ---------------------------------------------------------------------------
// Kernel 1: E prep. ek (FROZEN pairwise-8), split-bf16 swizzled chunks for
// MFMA staging, Etg[c][k] transpose (coalesced fallback reads). Zeroes both
// uncertain-row counters.
// ---------------------------------------------------------------------------
__global__ __launch_bounds__(256) void eprep2(const float* __restrict__ E,
                                              float* __restrict__ ek,
                                              short* __restrict__ EbfS,
                                              float* __restrict__ Etg,
                                              int* __restrict__ ucnt) {
#pragma clang fp contract(off)
    if (blockIdx.x == 0 && threadIdx.x < 2) ucnt[threadIdx.x] = 0;
    int k = blockIdx.x * 256 + threadIdx.x;
    const float* e = E + k * C;
    float ev[C];
#pragma unroll
    for (int c4 = 0; c4 < 16; ++c4) {
        float4 v = *(const float4*)(e + c4 * 4);
        ev[c4 * 4 + 0] = v.x; ev[c4 * 4 + 1] = v.y;
        ev[c4 * 4 + 2] = v.z; ev[c4 * 4 + 3] = v.w;
    }
    float r[8];
#pragma unroll
    for (int j = 0; j < 8; ++j) r[j] = ev[j] * ev[j];
#pragma unroll
    for (int i = 8; i < C; i += 8)
#pragma unroll
        for (int j = 0; j < 8; ++j) r[j] += ev[i + j] * ev[i + j];
    ek[k] = ((r[0] + r[1]) + (r[2] + r[3])) + ((r[4] + r[5]) + (r[6] + r[7]));

#pragma unroll
    for (int c = 0; c < C; ++c) Etg[c * K + k] = ev[c];   // coalesced per c

    unsigned short hi[C], lo[C];
#pragma unroll
    for (int c = 0; c < C; ++c) {
        unsigned short h = f2bf(ev[c]);
        hi[c] = h;
        lo[c] = f2bf(ev[c] - bf2f(h));
    }
#pragma unroll
    for (int ci = 0; ci < 16; ++ci) {
        int p = ci >> 3, c0 = (ci & 7) * 8;
        short8 v;
#pragma unroll
        for (int e2 = 0; e2 < 8; ++e2)
            v[e2] = (short)(p ? lo[c0 + e2] : hi[c0 + e2]);
        int slot = k * 16 + (ci ^ (k & 7));
        *(short8*)&EbfS[slot * 8] = v;
    }
}

// ---------------------------------------------------------------------------
// Kernel 2: MFMA argmin (R11-validated trusted path: R11 passed with rows
// at gap>2.5e-4 trusted from this exact compute). Self-check: 6 exact dots
// (rt0 regs0-3, rt1 reg0, last-tile reg0). Flag rows -> ulistA; gap rows ->
// ulistB.
// ---------------------------------------------------------------------------
__global__ __launch_bounds__(256, 2) void vq_mfma(const float* __restrict__ Z,
                                                  const float* __restrict__ Efp,
                                                  const float* __restrict__ ek,
                                                  const short* __restrict__ EbfS,
                                                  int* __restrict__ besti,
                                                  int* __restrict__ ulistA,
                                                  int* __restrict__ ulistB,
                                                  int* __restrict__ ucnt) {
#pragma clang fp contract(off)
    __shared__ float SA[8192];             // ZtF then E-tile (16KB used)
    __shared__ unsigned short Zb[16384];   // [128n][pl*64+c] bf16 planes
    __shared__ int flagLds;

    const int t = threadIdx.x;
    const int wave = t >> 6, lane = t & 63;
    const int n0 = blockIdx.x * MT;
    const int b = n0 >> 12;
    const int hw0 = n0 & 4095;
    const float* zbase = Z + b * (C * HW) + hw0;
    if (t == 0) flagLds = 0;

#pragma unroll
    for (int r = 0; r < 8; ++r) {
        int idx4 = r * 256 + t;
        int c = idx4 >> 5, n4 = idx4 & 31;
        float4 v = *(const float4*)(zbase + c * HW + n4 * 4);
        *(float4*)(&SA[c * MT + n4 * 4]) = v;
    }
    __syncthreads();

    const int wr = wave * 32;
    float chkA0 = 0, chkA1 = 0, chkA2 = 0, chkA3 = 0, chkB = 0, chkC = 0;
    {
        int rbase = wr + ((lane >> 4) << 2);
        const float* epA = Efp + (lane & 15) * C;
        const float* epC = Efp + (960 + (lane & 15)) * C;
#pragma unroll 8
        for (int c = 0; c < C; ++c) {
            float eA = epA[c], eC = epC[c];
            float z0 = SA[c * MT + rbase + 0];
            float z1 = SA[c * MT + rbase + 1];
            float z2 = SA[c * MT + rbase + 2];
            float z3 = SA[c * MT + rbase + 3];
            float zB = SA[c * MT + rbase + 16];
            chkA0 = __builtin_fmaf(z0, eA, chkA0);
            chkA1 = __builtin_fmaf(z1, eA, chkA1);
            chkA2 = __builtin_fmaf(z2, eA, chkA2);
            chkA3 = __builtin_fmaf(z3, eA, chkA3);
            chkB  = __builtin_fmaf(zB, eA, chkB);
            chkC  = __builtin_fmaf(z0, eC, chkC);
        }
    }
    {
        int r = t & 127, p = t >> 7;
#pragma unroll
        for (int c8 = 0; c8 < 8; ++c8) {
            short8 v;
#pragma unroll
            for (int e2 = 0; e2 < 8; ++e2) {
                float z = SA[(c8 * 8 + e2) * MT + r];
                unsigned short h = f2bf(z);
                v[e2] = (short)(p ? f2bf(z - bf2f(h)) : h);
            }
            *(short8*)&Zb[r * 128 + p * 64 + c8 * 8] = v;
        }
    }
    __syncthreads();   // ZtF dead; Zb ready

    short8 af[2][2][2];
#pragma unroll
    for (int rt = 0; rt < 2; ++rt)
#pragma unroll
        for (int ks = 0; ks < 2; ++ks)
#pragma unroll
            for (int p = 0; p < 2; ++p)
                af[rt][ks][p] = *(const short8*)&Zb[(wr + rt * 16 + (lane & 15)) * 128
                                                   + p * 64 + ks * 32 + ((lane >> 4) << 3)];

#pragma unroll
    for (int p2 = 0; p2 < 4; ++p2) {
        int q = wave * 4 + p2;
        const char* gsrc = (const char*)EbfS + q * 1024 + lane * 16;
        __builtin_amdgcn_global_load_lds((gas_ptr)gsrc,
                                         (las_ptr)((char*)SA + q * 1024), 16, 0, 0);
    }
    __syncthreads();

    float d1f[8], d2f[8];
    int k1[8];
#pragma unroll
    for (int s = 0; s < 8; ++s) { d1f[s] = __builtin_inff(); d2f[s] = __builtin_inff(); k1[s] = 0; }

#pragma unroll 1
    for (int tau = 0; tau < NT2; ++tau) {
#pragma unroll 1
        for (int cg = 0; cg < 4; ++cg) {
            int kl = cg * 16 + (lane & 15);
            int kg = tau * KT2 + kl;
            float ekv = ek[kg];
            short8 bf_[2][2];
#pragma unroll
            for (int ks = 0; ks < 2; ++ks)
#pragma unroll
                for (int p = 0; p < 2; ++p) {
                    int ci = p * 8 + ks * 4 + (lane >> 4);
                    int sca = kl * 16 + (ci ^ (kl & 7));
                    bf_[ks][p] = *(const short8*)((const char*)SA + sca * 16);
                }
#pragma unroll
            for (int rt = 0; rt < 2; ++rt) {
                f32x4 acc = {0.0f, 0.0f, 0.0f, 0.0f};
                acc = __builtin_amdgcn_mfma_f32_16x16x32_bf16(af[rt][0][0], bf_[0][0], acc, 0, 0, 0);
                acc = __builtin_amdgcn_mfma_f32_16x16x32_bf16(af[rt][0][0], bf_[0][1], acc, 0, 0, 0);
                acc = __builtin_amdgcn_mfma_f32_16x16x32_bf16(af[rt][0][1], bf_[0][0], acc, 0, 0, 0);
                acc = __builtin_amdgcn_mfma_f32_16x16x32_bf16(af[rt][1][0], bf_[1][0], acc, 0, 0, 0);
                acc = __builtin_amdgcn_mfma_f32_16x16x32_bf16(af[rt][1][0], bf_[1][1], acc, 0, 0, 0);
                acc = __builtin_amdgcn_mfma_f32_16x16x32_bf16(af[rt][1][1], bf_[1][0], acc, 0, 0, 0);
                if (tau == 0 && cg == 0) {
                    if (rt == 0) {
                        if (__builtin_fabsf(acc[0] - chkA0) > CHK_THR ||
                            __builtin_fabsf(acc[1] - chkA1) > CHK_THR ||
                            __builtin_fabsf(acc[2] - chkA2) > CHK_THR ||
                            __builtin_fabsf(acc[3] - chkA3) > CHK_THR) flagLds = 1;
                    } else {
                        if (__builtin_fabsf(acc[0] - chkB) > CHK_THR) flagLds = 1;
                    }
                }
                if (tau == NT2 - 1 && cg == 0 && rt == 0) {
                    if (__builtin_fabsf(acc[0] - chkC) > CHK_THR) flagLds = 1;
                }
#pragma unroll
                for (int j = 0; j < 4; ++j) {
                    float d = __builtin_fmaf(-2.0f, acc[j], ekv);
                    int s = rt * 4 + j;
                    if (d < d1f[s]) { d2f[s] = d1f[s]; d1f[s] = d; k1[s] = kg; }
                    else if (d < d2f[s]) { d2f[s] = d; }
                }
            }
        }
        __syncthreads();
        if (tau + 1 < NT2) {
#pragma unroll
            for (int p2 = 0; p2 < 4; ++p2) {
                int q = wave * 4 + p2;
                const char* gsrc = (const char*)EbfS + (tau + 1) * 16384 + q * 1024 + lane * 16;
                __builtin_amdgcn_global_load_lds((gas_ptr)gsrc,
                                                 (las_ptr)((char*)SA + q * 1024), 16, 0, 0);
            }
        }
        __syncthreads();
    }

#pragma unroll
    for (int s = 0; s < 8; ++s) {
        u64 pk = packdk(d1f[s], k1[s]);
        float d1 = d1f[s], d2 = d2f[s];
#pragma unroll
        for (int m = 1; m <= 8; m <<= 1) {
            u64 po = __shfl_xor(pk, m, 64);
            float d1o = __shfl_xor(d1, m, 64);
            float d2o = __shfl_xor(d2, m, 64);
            d2 = fminf(fminf(d2, d2o), fmaxf(d1, d1o));
            d1 = fminf(d1, d1o);
            pk = po < pk ? po : pk;
        }
        d1f[s] = d1; d2f[s] = d2; k1[s] = (int)(pk & 0xFFFFFFFFull);
    }
    int flg = flagLds;
    if ((lane & 15) == 0) {
#pragma unroll
        for (int s = 0; s < 8; ++s) {
            int rt = s >> 2, j = s & 3;
            int n = n0 + wr + rt * 16 + ((lane >> 4) << 2) + j;
            besti[n] = k1[s];
            float gap = d2f[s] - d1f[s];
            if (flg) {
                int ix = atomicAdd(&ucnt[0], 1);
                ulistA[ix] = n;
            } else if (!(gap > GAP_THR)) {
                int ix = atomicAdd(&ucnt[1], 1);
                ulistB[ix] = n;
            }
        }
    }
}

// ---------------------------------------------------------------------------
// Fast exact fallback: block-per-row, z in LDS, codes over threads reading
// Etg[c][k] COALESCED (Etg now uncorrupted). Frozen chain.
// ---------------------------------------------------------------------------
__device__ __forceinline__ void fb_body(const float* __restrict__ Z,
                                        const float* __restrict__ Etg,
                                        const float* __restrict__ ek,
                                        const int* __restrict__ ulist,
                                        const int* __restrict__ pcnt,
                                        int* __restrict__ besti) {
#pragma clang fp contract(off)
    __shared__ float zs[C];
    __shared__ u64 wmin[4];
    const int t = threadIdx.x;
    const int wave = t >> 6, lane = t & 63;
    const int cnt = *pcnt;
    for (int i = blockIdx.x; i < cnt; i += gridDim.x) {
        const int n = ulist[i];
        const int b = n >> 12, hw = n & 4095;
        __syncthreads();
        if (t < C) zs[t] = Z[b * (C * HW) + t * HW + hw];
        __syncthreads();
        float r[8];
#pragma unroll
        for (int j = 0; j < 8; ++j) r[j] = zs[j] * zs[j];
#pragma unroll
        for (int q = 8; q < C; q += 8)
#pragma unroll
            for (int j = 0; j < 8; ++j) r[j] += zs[q + j] * zs[q + j];
        const float zn = ((r[0] + r[1]) + (r[2] + r[3])) + ((r[4] + r[5]) + (r[6] + r[7]));
        u64 best = ~0ull;
#pragma unroll
        for (int q = 0; q < 4; ++q) {
            const int k = q * 256 + t;
            float a = 0.0f;
#pragma unroll 8
            for (int c = 0; c < C; ++c)
                a = __builtin_fmaf(zs[c], Etg[c * K + k], a);
            float A = zn + ek[k];
            float d = A - 2.0f * a;
            u64 p = packdk(d, k);
            if (p < best) best = p;
        }
#pragma unroll
        for (int m = 1; m <= 32; m <<= 1) {
            u64 o = __shfl_xor(best, m, 64);
            best = o < best ? o : best;
        }
        if (lane == 0) wmin[wave] = best;
        __syncthreads();
        if (t == 0) {
            u64 v = wmin[0];
            if (wmin[1] < v) v = wmin[1];
            if (wmin[2] < v) v = wmin[2];
            if (wmin[3] < v) v = wmin[3];
            besti[n] = (int)(v & 0xFFFFFFFFull);
        }
    }
}
__global__ __launch_bounds__(256) void vq_fb_flag(const float* __restrict__ Z,
                                                  const float* __restrict__ Etg,
                                                  const float* __restrict__ ek,
                                                  const int* __restrict__ ulist,
                                                  const int* __restrict__ ucnt,
                                                  int* __restrict__ besti) {
    fb_body(Z, Etg, ek, ulist, ucnt + 0, besti);
}
__global__ __launch_bounds__(256) void vq_fb_gap(const float* __restrict__ Z,
                                                 const float* __restrict__ Etg,
                                                 const float* __restrict__ ek,
                                                 const int* __restrict__ ulist,
                                                 const int* __restrict__ ucnt,
                                                 int* __restrict__ besti) {
    fb_body(Z, Etg, ek, ulist, ucnt + 1, besti);
}

// ---------------------------------------------------------------------------
// Epilogue for ALL rows (FROZEN, R11-verified).
// ---------------------------------------------------------------------------
__global__ __launch_bounds__(256) void vq_epilogue2(const float* __restrict__ Z,
                                                    const float* __restrict__ E,
                                                    const int* __restrict__ besti,
                                                    float* __restrict__ out,
                                                    float* __restrict__ rowloss) {
#pragma clang fp contract(off)
    int n = blockIdx.x * 256 + threadIdx.x;
    int b = n >> 12, hw = n & 4095;
    int best = besti[n];
    const float* zp = Z + b * (C * HW) + hw;
    const float4* eb4 = (const float4*)(E + best * C);
    float* o0 = out + b * (C * HW) + hw;
    float ls = 0.0f;
#pragma unroll
    for (int c4 = 0; c4 < 16; ++c4) {
        float4 e4 = eb4[c4];
        int cb = c4 * 4;
        float z0 = zp[(cb + 0) * HW], z1 = zp[(cb + 1) * HW];
        float z2 = zp[(cb + 2) * HW], z3 = zp[(cb + 3) * HW];
        float f0 = e4.x - z0; o0[(cb + 0) * HW] = z0 + f0; ls += f0 * f0;
        float f1 = e4.y - z1; o0[(cb + 1) * HW] = z1 + f1; ls += f1 * f1;
        float f2 = e4.z - z2; o0[(cb + 2) * HW] = z2 + f2; ls += f2 * f2;
        float f3 = e4.w - z3; o0[(cb + 3) * HW] = z3 + f3; ls += f3 * f3;
    }
    out[OUT0 + n] = (float)best;
    rowloss[n] = ls;
}

__global__ __launch_bounds__(256) void loss2(const float* __restrict__ rowloss,
                                             float* __restrict__ out) {
    __shared__ double sm[256];
    int t = threadIdx.x;
    double s = 0.0;
    for (int i = t; i < N_TOTAL; i += 256) s += (double)rowloss[i];
    sm[t] = s;
    __syncthreads();
    for (int o = 128; o > 0; o >>= 1) {
        if (t < o) sm[t] += sm[t + o];
        __syncthreads();
    }
    if (t == 0) {
        float m = (float)(sm[0] * (1.0 / 8388608.0));
        out[OUT0 + N_TOTAL] = m + 0.25f * m;
    }
}

// ---------------------------------------------------------------------------
// Small-ws fallback path (R2-proven exact kernels, FROZEN).
// ---------------------------------------------------------------------------
__global__ __launch_bounds__(256) void ek_kernel(const float* __restrict__ E,
                                                 float* __restrict__ ek) {
#pragma clang fp contract(off)
    int k = blockIdx.x * 256 + threadIdx.x;
    if (k >= K) return;
    const float* e = E + k * C;
    float r[8];
#pragma unroll
    for (int j = 0; j < 8; ++j) { float v = e[j]; r[j] = v * v; }
#pragma unroll
    for (int i = 8; i < C; i += 8)
#pragma unroll
        for (int j = 0; j < 8; ++j) { float v = e[i + j]; r[j] += v * v; }
    ek[k] = ((r[0] + r[1]) + (r[2] + r[3])) + ((r[4] + r[5]) + (r[6] + r[7]));
}

__global__ __launch_bounds__(256, 4) void vq_combined(const float* __restrict__ Z,
                                                      const float* __restrict__ E,
                                                      const float* __restrict__ ek,
                                                      float* __restrict__ out,
                                                      float* __restrict__ partials) {
#pragma clang fp contract(off)
    int n = blockIdx.x * 256 + threadIdx.x;
    int b = n >> 12, hw = n & 4095;
    const float* zp = Z + b * (C * HW) + hw;
    float z[C];
#pragma unroll
    for (int c = 0; c < C; ++c) z[c] = zp[c * HW];
    float zn;
    {
        float r[8];
#pragma unroll
        for (int j = 0; j < 8; ++j) r[j] = z[j] * z[j];
#pragma unroll
        for (int i = 8; i < C; i += 8)
#pragma unroll
            for (int j = 0; j < 8; ++j) r[j] += z[i + j] * z[i + j];
        zn = ((r[0] + r[1]) + (r[2] + r[3])) + ((r[4] + r[5]) + (r[6] + r[7]));
    }
    float dmin = __builtin_inff();
    int best = 0;
#pragma unroll 1
    for (int k = 0; k < K; k += 4) {
        const float* e0 = E + k * C;
        float a0 = 0.0f, a1 = 0.0f, a2 = 0.0f, a3 = 0.0f;
#pragma unroll
        for (int c = 0; c < C; ++c) {
            float zc = z[c];
            a0 = __builtin_fmaf(zc, e0[c], a0);
            a1 = __builtin_fmaf(zc, e0[C + c], a1);
            a2 = __builtin_fmaf(zc, e0[2 * C + c], a2);
            a3 = __builtin_fmaf(zc, e0[3 * C + c], a3);
        }
        float A0 = zn + ek[k],     A1 = zn + ek[k + 1];
        float A2 = zn + ek[k + 2], A3 = zn + ek[k + 3];
        float d0 = A0 - 2.0f * a0, d1 = A1 - 2.0f * a1;
        float d2 = A2 - 2.0f * a2, d3 = A3 - 2.0f * a3;
        if (d0 < dmin) { dmin = d0; best = k; }
        if (d1 < dmin) { dmin = d1; best = k + 1; }
        if (d2 < dmin) { dmin = d2; best = k + 2; }
        if (d3 < dmin) { dmin = d3; best = k + 3; }
    }
    const float4* eb4 = (const float4*)(E + best * C);
    float* o0 = out + b * (C * HW) + hw;
    float ls = 0.0f;
#pragma unroll
    for (int c4 = 0; c4 < 16; ++c4) {
        float4 e4 = eb4[c4];
        int cb = c4 * 4;
        float f0 = e4.x - z[cb + 0]; o0[(cb + 0) * HW] = z[cb + 0] + f0; ls += f0 * f0;
        float f1 = e4.y - z[cb + 1]; o0[(cb + 1) * HW] = z[cb + 1] + f1; ls += f1 * f1;
        float f2 = e4.z - z[cb + 2]; o0[(cb + 2) * HW] = z[cb + 2] + f2; ls += f2 * f2;
        float f3 = e4.w - z[cb + 3]; o0[(cb + 3) * HW] = z[cb + 3] + f3; ls += f3 * f3;
    }
    out[OUT0 + n] = (float)best;
#pragma unroll
    for (int off = 32; off > 0; off >>= 1) ls += __shfl_xor(ls, off, 64);
    if ((threadIdx.x & 63) == 0) partials[n >> 6] = ls;
}

__global__ __launch_bounds__(256) void loss_kernel(const float* __restrict__ partials,
                                                   float* __restrict__ out) {
    __shared__ double sm[256];
    int t = threadIdx.x;
    double s = 0.0;
    for (int i = t; i < (N_TOTAL / 64); i += 256) s += (double)partials[i];
    sm[t] = s;
    __syncthreads();
    for (int o = 128; o > 0; o >>= 1) {
        if (t < o) sm[t] += sm[t + o];
        __syncthreads();
    }
    if (t == 0) {
        float m = (float)(sm[0] * (1.0 / 8388608.0));
        out[OUT0 + N_TOTAL] = m + 0.25f * m;
    }
}

extern "C" void kernel_launch(void* const* d_in, const int* in_sizes, int n_in,
                              void* d_out, int out_size, void* d_ws, size_t ws_size,
                              hipStream_t stream) {
    const float* Z = (const float*)d_in[0];
    const float* E = (const float*)d_in[1];
    float* out = (float*)d_out;
    float* ws = (float*)d_ws;
    float* ek = ws + WS_EK;

    if (ws_size >= (size_t)WS_NEED2 * sizeof(float)) {
        int* besti   = (int*)(ws + WS_BESTI);
        int* ulistA  = (int*)(ws + WS_ULISTA);
        int* ulistB  = (int*)(ws + WS_ULISTB);
        int* ucnt    = (int*)(ws + WS_UCNT);
        short* EbfS  = (short*)(ws + WS_EBF);
        float* Etg   = ws + WS_ETG;
        float* rowloss = ws + WS_ROWLOSS;   // aliases ulistA (dead by then)

        hipLaunchKernelGGL(eprep2, dim3(K / 256), dim3(256), 0, stream,
                           E, ek, EbfS, Etg, ucnt);
        hipLaunchKernelGGL(vq_mfma, dim3(N_TOTAL / MT), dim3(256), 0, stream,
                           Z, E, ek, EbfS, besti, ulistA, ulistB, ucnt);
        hipLaunchKernelGGL(vq_fb_flag, dim3(2048), dim3(256), 0, stream,
                           Z, Etg, ek, ulistA, ucnt, besti);
        hipLaunchKernelGGL(vq_fb_gap, dim3(2048), dim3(256), 0, stream,
                           Z, Etg, ek, ulistB, ucnt, besti);
        hipLaunchKernelGGL(vq_epilogue2, dim3(N_TOTAL / 256), dim3(256), 0, stream,
                           Z, E, besti, out, rowloss);
        hipLaunchKernelGGL(loss2, dim3(1), dim3(256), 0, stream, rowloss, out);
    } else {
        float* partials = ws + 1024;
        hipLaunchKernelGGL(ek_kernel, dim3(4), dim3(256), 0, stream, E, ek);
        hipLaunchKernelGGL(vq_combined, dim3(N_TOTAL / 256), dim3(256), 0, stream,
                           Z, E, ek, out, partials);
        hipLaunchKernelGGL(loss_kernel, dim3(1), dim3(256), 0, stream, partials, out);
    }
}

// Round 14
// 559.850 us; speedup vs baseline: 1.3459x; 1.2816x over previous
//
#include <hip/hip_runtime.h>

#define C 64
#define K 1024
#define HW 4096
#define N_TOTAL 131072   // 32*64*64
#define OUT0 8388608     // 32*64*64*64 (z_q_out elements)
#define MT 128           // n-rows per block
#define KT2 64           // codes per MFMA k-tile
#define NT2 16

#define GAP_THR 1.5e-4f  // certainty margin (differential rounding <= ~4e-5)
#define CHK_THR 1e-4f    // calibration threshold (|S-a|~1e-6 right, ~1e-2 wrong)

// d_ws float offsets. 526352 f = 2.105 MB <= proven ws (R3 path used 2.109 MB).
#define WS_EK        0         // 1024 f
#define WS_BESTI     1024      // 131072 int
#define WS_ULISTB    132096    // 131072 int (gap rows)
#define WS_UCNT      263168    // 16 int
#define WS_BFLAG     263184    // 1024 int
#define WS_EBF       264208    // 65536 f = 262144 B bf16 chunks
#define WS_ETG       329744    // 65536 f
#define WS_ROWLOSS   395280    // 131072 f
#define WS_NEED2     526352

typedef unsigned int u32;
typedef unsigned long long u64;
typedef __attribute__((ext_vector_type(8))) short short8;
typedef __attribute__((ext_vector_type(4))) float f32x4;
typedef const __attribute__((address_space(1))) void* gas_ptr;
typedef __attribute__((address_space(3))) void* las_ptr;

__device__ __forceinline__ u64 packdk(float d, int k) {
    u32 b = __float_as_uint(d);
    u32 m = b ^ ((u32)((int)b >> 31) | 0x80000000u);
    return ((u64)m << 32) | (u32)k;
}
__device__ __forceinline__ unsigned short f2bf(float x) {
    u32 u = __float_as_uint(x);
    return (unsigned short)((u + 0x7FFFu + ((u >> 16) & 1u)) >> 16);
}
__device__ __forceinline__ float bf2f(unsigned short h) {
    u32 u = ((u32)h) << 16;
    return __uint_as_float(u);
}

// ---------------------------------------------------------------------------
// Kernel 1: E prep (R13-verified): ek frozen pairwise-8; split-bf16 swizzled
// chunks (slot = k*16 + (ci ^ (k&7))); Etg[c][k]; zero counters.
// ---------------------------------------------------------------------------
__global__ __launch_bounds__(256) void eprep2(const float* __restrict__ E,
                                              float* __restrict__ ek,
                                              short* __restrict__ EbfS,
                                              float* __restrict__ Etg,
                                              int* __restrict__ ucnt) {
#pragma clang fp contract(off)
    if (blockIdx.x == 0 && threadIdx.x < 2) ucnt[threadIdx.x] = 0;
    int k = blockIdx.x * 256 + threadIdx.x;
    const float* e = E + k * C;
    float ev[C];
#pragma unroll
    for (int c4 = 0; c4 < 16; ++c4) {
        float4 v = *(const float4*)(e + c4 * 4);
        ev[c4 * 4 + 0] = v.x; ev[c4 * 4 + 1] = v.y;
        ev[c4 * 4 + 2] = v.z; ev[c4 * 4 + 3] = v.w;
    }
    float r[8];
#pragma unroll
    for (int j = 0; j < 8; ++j) r[j] = ev[j] * ev[j];
#pragma unroll
    for (int i = 8; i < C; i += 8)
#pragma unroll
        for (int j = 0; j < 8; ++j) r[j] += ev[i + j] * ev[i + j];
    ek[k] = ((r[0] + r[1]) + (r[2] + r[3])) + ((r[4] + r[5]) + (r[6] + r[7]));
#pragma unroll
    for (int c = 0; c < C; ++c) Etg[c * K + k] = ev[c];

    unsigned short hi[C], lo[C];
#pragma unroll
    for (int c = 0; c < C; ++c) {
        unsigned short h = f2bf(ev[c]);
        hi[c] = h;
        lo[c] = f2bf(ev[c] - bf2f(h));
    }
#pragma unroll
    for (int ci = 0; ci < 16; ++ci) {
        int p = ci >> 3, c0 = (ci & 7) * 8;
        short8 v;
#pragma unroll
        for (int e2 = 0; e2 < 8; ++e2)
            v[e2] = (short)(p ? lo[c0 + e2] : hi[c0 + e2]);
        int slot = k * 16 + (ci ^ (k & 7));
        *(short8*)&EbfS[slot * 8] = v;
    }
}

// ---------------------------------------------------------------------------
// Kernel 2: MFMA argmin with DUAL-INTERPRETATION CALIBRATION.
// I1: acc[j] <-> (row wr+rt*16+(l>>4)*4+j, code cg16+(l&15))
// I2: acc[j] <-> (row wr+rt*16+(l&15),     code cg16+(l>>4)*4+j)
// Pre-pass votes per block; mode-correct ek lookup; kbase stored, decoded
// per mode at the end. Zb XOR-swizzled (slot = c8 ^ (row&7)) on write+read
// -> bank sweep (R13 had 6.9M conflicts from uniform bank groups).
// If no mode matches or staged-data integrity check fails -> bflag -> the
// R10-proven exact GEMM recomputes that block. Gap rows -> ulistB.
// ---------------------------------------------------------------------------
__global__ __launch_bounds__(256, 2) void vq_mfma(const float* __restrict__ Z,
                                                  const float* __restrict__ Efp,
                                                  const float* __restrict__ ek,
                                                  const short* __restrict__ EbfS,
                                                  int* __restrict__ besti,
                                                  int* __restrict__ ulistB,
                                                  int* __restrict__ ucnt,
                                                  int* __restrict__ bflag) {
#pragma clang fp contract(off)
    __shared__ float SA[8192];             // ZtF fp32, then E-tile chunks
    __shared__ unsigned short Zb[16384];   // split-bf16 A planes (swizzled)
    __shared__ int vmode[4];
    __shared__ int anyBad;

    const int t = threadIdx.x;
    const int wave = t >> 6, lane = t & 63;
    const int gidx = lane >> 4;            // 0..3
    const int m15 = lane & 15;             // 0..15
    const int wr = wave * 32;
    const int n0 = blockIdx.x * MT;
    const int b = n0 >> 12;
    const int hw0 = n0 & 4095;
    const float* zbase = Z + b * (C * HW) + hw0;
    if (t == 0) anyBad = 0;

    // ---- stage ZtF fp32 [c][n] (coalesced) ----
#pragma unroll
    for (int r = 0; r < 8; ++r) {
        int idx4 = r * 256 + t;
        int c = idx4 >> 5, n4 = idx4 & 31;
        float4 v = *(const float4*)(zbase + c * HW + n4 * 4);
        *(float4*)(&SA[c * MT + n4 * 4]) = v;
    }
    __syncthreads();

    // ---- 16 exact check dots (frozen seq-fma) covering both hypotheses ----
    float chk1[2][4], chk2[2][4];
#pragma unroll
    for (int rt = 0; rt < 2; ++rt)
#pragma unroll
        for (int j = 0; j < 4; ++j) { chk1[rt][j] = 0.0f; chk2[rt][j] = 0.0f; }
    {
        const float* e1 = Efp + m15 * C;
#pragma unroll 4
        for (int c = 0; c < C; ++c) {
            float e1v = e1[c];
            float e2v0 = Efp[(gidx * 4 + 0) * C + c];
            float e2v1 = Efp[(gidx * 4 + 1) * C + c];
            float e2v2 = Efp[(gidx * 4 + 2) * C + c];
            float e2v3 = Efp[(gidx * 4 + 3) * C + c];
#pragma unroll
            for (int rt = 0; rt < 2; ++rt) {
                int rb = wr + rt * 16;
                float z0 = SA[c * MT + rb + gidx * 4 + 0];
                float z1 = SA[c * MT + rb + gidx * 4 + 1];
                float z2 = SA[c * MT + rb + gidx * 4 + 2];
                float z3 = SA[c * MT + rb + gidx * 4 + 3];
                chk1[rt][0] = __builtin_fmaf(z0, e1v, chk1[rt][0]);
                chk1[rt][1] = __builtin_fmaf(z1, e1v, chk1[rt][1]);
                chk1[rt][2] = __builtin_fmaf(z2, e1v, chk1[rt][2]);
                chk1[rt][3] = __builtin_fmaf(z3, e1v, chk1[rt][3]);
                float zr = SA[c * MT + rb + m15];
                chk2[rt][0] = __builtin_fmaf(zr, e2v0, chk2[rt][0]);
                chk2[rt][1] = __builtin_fmaf(zr, e2v1, chk2[rt][1]);
                chk2[rt][2] = __builtin_fmaf(zr, e2v2, chk2[rt][2]);
                chk2[rt][3] = __builtin_fmaf(zr, e2v3, chk2[rt][3]);
            }
        }
    }
    // ---- convert Z to split-bf16 planes, Zb chunk slot = c8 ^ (row&7) ----
    {
        int r = t & 127, p = t >> 7;
#pragma unroll
        for (int c8 = 0; c8 < 8; ++c8) {
            short8 v;
#pragma unroll
            for (int e2 = 0; e2 < 8; ++e2) {
                float z = SA[(c8 * 8 + e2) * MT + r];
                unsigned short h = f2bf(z);
                v[e2] = (short)(p ? f2bf(z - bf2f(h)) : h);
            }
            int slot = c8 ^ (r & 7);
            *(short8*)&Zb[r * 128 + p * 64 + slot * 8] = v;
        }
    }
    __syncthreads();

    // ---- A fragments (swizzled read; row&7 == m15&7) ----
    short8 af[2][2][2];
#pragma unroll
    for (int rt = 0; rt < 2; ++rt)
#pragma unroll
        for (int ks = 0; ks < 2; ++ks)
#pragma unroll
            for (int p = 0; p < 2; ++p) {
                int row = wr + rt * 16 + m15;
                int slot = (ks * 4 + gidx) ^ (m15 & 7);
                af[rt][ks][p] = *(const short8*)&Zb[row * 128 + p * 64 + slot * 8];
            }

    // ---- DMA E-tile 0 (R13 pattern) ----
#pragma unroll
    for (int p2 = 0; p2 < 4; ++p2) {
        int q = wave * 4 + p2;
        const char* gsrc = (const char*)EbfS + q * 1024 + lane * 16;
        __builtin_amdgcn_global_load_lds((gas_ptr)gsrc,
                                         (las_ptr)((char*)SA + q * 1024), 16, 0, 0);
    }
    __syncthreads();

#define LOAD_BF(bf_, cgv)                                                   \
    {                                                                       \
        int kl_ = (cgv) * 16 + m15;                                         \
        _Pragma("unroll")                                                   \
        for (int ks = 0; ks < 2; ++ks)                                      \
            _Pragma("unroll")                                               \
            for (int p = 0; p < 2; ++p) {                                   \
                int ci = p * 8 + ks * 4 + gidx;                             \
                int sca = kl_ * 16 + (ci ^ (m15 & 7));                      \
                bf_[ks][p] = *(const short8*)((const char*)SA + sca * 16);  \
            }                                                               \
    }
#define MFMA6(acc, rt, bf_)                                                          \
    acc = __builtin_amdgcn_mfma_f32_16x16x32_bf16(af[rt][0][0], bf_[0][0], acc, 0, 0, 0); \
    acc = __builtin_amdgcn_mfma_f32_16x16x32_bf16(af[rt][0][0], bf_[0][1], acc, 0, 0, 0); \
    acc = __builtin_amdgcn_mfma_f32_16x16x32_bf16(af[rt][0][1], bf_[0][0], acc, 0, 0, 0); \
    acc = __builtin_amdgcn_mfma_f32_16x16x32_bf16(af[rt][1][0], bf_[1][0], acc, 0, 0, 0); \
    acc = __builtin_amdgcn_mfma_f32_16x16x32_bf16(af[rt][1][0], bf_[1][1], acc, 0, 0, 0); \
    acc = __builtin_amdgcn_mfma_f32_16x16x32_bf16(af[rt][1][1], bf_[1][0], acc, 0, 0, 0);

    // ---- pre-pass: calibrate interpretation on (tau0, cg0) ----
    {
        short8 bf_[2][2];
        LOAD_BF(bf_, 0);
        int ok1 = 1, ok2 = 1;
#pragma unroll
        for (int rt = 0; rt < 2; ++rt) {
            f32x4 acc = {0.0f, 0.0f, 0.0f, 0.0f};
            MFMA6(acc, rt, bf_);
#pragma unroll
            for (int j = 0; j < 4; ++j) {
                ok1 &= (__builtin_fabsf(acc[j] - chk1[rt][j]) < CHK_THR) ? 1 : 0;
                ok2 &= (__builtin_fabsf(acc[j] - chk2[rt][j]) < CHK_THR) ? 1 : 0;
            }
        }
        int a1 = __all(ok1), a2 = __all(ok2);
        if (lane == 0) vmode[wave] = a1 ? 1 : (a2 ? 2 : 0);
    }
    __syncthreads();
    int mode = vmode[0];
    if (vmode[1] != mode || vmode[2] != mode || vmode[3] != mode) mode = 0;
    if (mode == 0) {                       // layout unknown -> R10-exact redo
        if (t == 0) bflag[blockIdx.x] = 1;
        return;
    }

    float d1f[8], d2f[8];
    int kb[8];
#pragma unroll
    for (int s = 0; s < 8; ++s) { d1f[s] = __builtin_inff(); d2f[s] = __builtin_inff(); kb[s] = 0; }

#pragma unroll 1
    for (int tau = 0; tau < NT2; ++tau) {
#pragma unroll 1
        for (int cg = 0; cg < 4; ++cg) {
            const int base = tau * 64 + cg * 16;
            float ekvS[8];
            if (mode == 1) {
                float v = ek[base + m15];
#pragma unroll
                for (int s = 0; s < 8; ++s) ekvS[s] = v;
            } else {
                float e0 = ek[base + gidx * 4 + 0];
                float e1 = ek[base + gidx * 4 + 1];
                float e2 = ek[base + gidx * 4 + 2];
                float e3 = ek[base + gidx * 4 + 3];
                ekvS[0] = e0; ekvS[1] = e1; ekvS[2] = e2; ekvS[3] = e3;
                ekvS[4] = e0; ekvS[5] = e1; ekvS[6] = e2; ekvS[7] = e3;
            }
            short8 bf_[2][2];
            LOAD_BF(bf_, cg);
#pragma unroll
            for (int rt = 0; rt < 2; ++rt) {
                f32x4 acc = {0.0f, 0.0f, 0.0f, 0.0f};
                MFMA6(acc, rt, bf_);
#pragma unroll
                for (int j = 0; j < 4; ++j) {
                    int s = rt * 4 + j;
                    float d = __builtin_fmaf(-2.0f, acc[j], ekvS[s]);
                    if (d < d1f[s]) { d2f[s] = d1f[s]; d1f[s] = d; kb[s] = base; }
                    else if (d < d2f[s]) { d2f[s] = d; }
                }
            }
        }
        __syncthreads();
        if (tau + 1 < NT2) {
#pragma unroll
            for (int p2 = 0; p2 < 4; ++p2) {
                int q = wave * 4 + p2;
                const char* gsrc = (const char*)EbfS + (tau + 1) * 16384 + q * 1024 + lane * 16;
                __builtin_amdgcn_global_load_lds((gas_ptr)gsrc,
                                                 (las_ptr)((char*)SA + q * 1024), 16, 0, 0);
            }
        }
        __syncthreads();
    }

    // ---- staged-data integrity check on the LAST tile (mode-independent) ----
    {
        int kl = m15;
        int kg = (NT2 - 1) * 64 + kl;
        int bad = 0;
#pragma unroll
        for (int pair = 0; pair < 2; ++pair) {
            int ks = pair, p = pair;
            int ci = p * 8 + ks * 4 + gidx;
            int sca = kl * 16 + (ci ^ (m15 & 7));
            short8 got = *(const short8*)((const char*)SA + sca * 16);
#pragma unroll
            for (int j = 0; j < 8; ++j) {
                int c = ks * 32 + gidx * 8 + j;
                float evv = Efp[kg * C + c];
                unsigned short h = f2bf(evv);
                unsigned short want = p ? f2bf(evv - bf2f(h)) : h;
                bad |= ((unsigned short)got[j] != want) ? 1 : 0;
            }
        }
        if (bad) anyBad = 1;
    }
    __syncthreads();
    int flag = anyBad;
    if (t == 0) bflag[blockIdx.x] = flag ? 1 : 0;
    if (flag) return;

    // ---- decode + reduce + write, per mode ----
    if (mode == 1) {
#pragma unroll
        for (int s = 0; s < 8; ++s) {
            u64 v = packdk(d1f[s], kb[s] + m15);
            float d1 = d1f[s], d2 = d2f[s];
#pragma unroll
            for (int mask = 1; mask <= 8; mask <<= 1) {
                u64 po = __shfl_xor(v, mask, 64);
                float d1o = __shfl_xor(d1, mask, 64);
                float d2o = __shfl_xor(d2, mask, 64);
                d2 = fminf(fminf(d2, d2o), fmaxf(d1, d1o));
                d1 = fminf(d1, d1o);
                if (po < v) v = po;
            }
            if (m15 == 0) {
                int n = n0 + wr + (s >> 2) * 16 + gidx * 4 + (s & 3);
                besti[n] = (int)(v & 0xFFFFFFFFu);
                if (!((d2 - d1) > GAP_THR)) {
                    int ix = atomicAdd(&ucnt[0], 1);
                    ulistB[ix] = n;
                }
            }
        }
    } else {
#pragma unroll
        for (int rt = 0; rt < 2; ++rt) {
            int s0 = rt * 4;
            u64 v = packdk(d1f[s0], kb[s0] + gidx * 4 + 0);
            float d1 = d1f[s0], d2 = d2f[s0];
#pragma unroll
            for (int j = 1; j < 4; ++j) {
                int s = s0 + j;
                u64 po = packdk(d1f[s], kb[s] + gidx * 4 + j);
                float d1o = d1f[s], d2o = d2f[s];
                d2 = fminf(fminf(d2, d2o), fmaxf(d1, d1o));
                d1 = fminf(d1, d1o);
                if (po < v) v = po;
            }
#pragma unroll
            for (int mask = 16; mask <= 32; mask <<= 1) {
                u64 po = __shfl_xor(v, mask, 64);
                float d1o = __shfl_xor(d1, mask, 64);
                float d2o = __shfl_xor(d2, mask, 64);
                d2 = fminf(fminf(d2, d2o), fmaxf(d1, d1o));
                d1 = fminf(d1, d1o);
                if (po < v) v = po;
            }
            if (gidx == 0) {
                int n = n0 + wr + rt * 16 + m15;
                besti[n] = (int)(v & 0xFFFFFFFFu);
                if (!((d2 - d1) > GAP_THR)) {
                    int ix = atomicAdd(&ucnt[0], 1);
                    ulistB[ix] = n;
                }
            }
        }
    }
#undef LOAD_BF
#undef MFMA6
}

// ---------------------------------------------------------------------------
// Kernel 3: R10-PROVEN exact GEMM (220us class) gated per flagged block.
// Verbatim R10 argmin (frozen numerics, absmax 0.0) writing besti only.
// ---------------------------------------------------------------------------
__global__ __launch_bounds__(256, 2) void vq_exact_block(const float* __restrict__ Z,
                                                         const float* __restrict__ Etg,
                                                         const float* __restrict__ ek,
                                                         const int* __restrict__ bflag,
                                                         int* __restrict__ besti) {
#pragma clang fp contract(off)
    if (bflag[blockIdx.x] == 0) return;
    __shared__ float Zt[C * MT];
    __shared__ float EtS[32 * 128];
    __shared__ float znbuf[MT];
    __shared__ u64 red[4][8][8];

    const int t = threadIdx.x;
    const int wave = t >> 6, lane = t & 63;
    const int n0 = blockIdx.x * MT;
    const int b = n0 >> 12;
    const int hw0 = n0 & 4095;
    const float* zbase = Z + b * (C * HW) + hw0;

#pragma unroll
    for (int r = 0; r < 8; ++r) {
        int idx4 = r * 256 + t;
        int c = idx4 >> 5, n4 = idx4 & 31;
        float4 v = *(const float4*)(zbase + c * HW + n4 * 4);
        *(float4*)(&Zt[c * MT + n4 * 4]) = v;
    }
#pragma unroll
    for (int p = 0; p < 4; ++p) {
        int q = wave * 4 + p;
        int c = 2 * q + (lane >> 5);
        const float* gsrc = Etg + c * K + (lane & 31) * 4;
        __builtin_amdgcn_global_load_lds((gas_ptr)gsrc, (las_ptr)&EtS[q * 256],
                                         16, 0, 0);
    }
    __syncthreads();

    if (t < MT) {
        float r8[8];
#pragma unroll
        for (int j = 0; j < 8; ++j) { float v = Zt[j * MT + t]; r8[j] = v * v; }
#pragma unroll
        for (int i = 1; i < 8; ++i)
#pragma unroll
            for (int j = 0; j < 8; ++j) { float v = Zt[(i * 8 + j) * MT + t]; r8[j] += v * v; }
        znbuf[t] = ((r8[0] + r8[1]) + (r8[2] + r8[3])) + ((r8[4] + r8[5]) + (r8[6] + r8[7]));
    }
    __syncthreads();

    const int i_l = lane & 7, j_l = lane >> 3;
    const int ig = ((wave & 1) << 3) | i_l;
    const int jg = ((wave >> 1) << 3) | j_l;

    float znm[8];
#pragma unroll
    for (int m = 0; m < 8; ++m) znm[m] = znbuf[ig * 8 + m];

    float dmin[8];
    int qb[8];
#pragma unroll
    for (int m = 0; m < 8; ++m) { dmin[m] = __builtin_inff(); qb[m] = 0; }

    float acc[8][8];
    float ekq[8];

#pragma unroll 1
    for (int s = 0; s < 16; ++s) {
        const int tile = s >> 1;
        const int h = s & 1;
        if (h == 0) {
            const float* ekp = ek + tile * 128 + jg * 8;
            float4 a = *(const float4*)ekp;
            float4 bq = *(const float4*)(ekp + 4);
            ekq[0] = a.x;  ekq[1] = a.y;  ekq[2] = a.z;  ekq[3] = a.w;
            ekq[4] = bq.x; ekq[5] = bq.y; ekq[6] = bq.z; ekq[7] = bq.w;
#pragma unroll
            for (int m = 0; m < 8; ++m)
#pragma unroll
                for (int q = 0; q < 8; ++q) acc[m][q] = 0.0f;
        }
        const int cbase = h * 32;
#pragma unroll 4
        for (int ch = 0; ch < 32; ++ch) {
            int c = cbase + ch;
            float4 za = *(const float4*)(&Zt[c * MT + ig * 8]);
            float4 zb = *(const float4*)(&Zt[c * MT + ig * 8 + 4]);
            float4 ea = *(const float4*)(&EtS[ch * 128 + jg * 8]);
            float4 eb = *(const float4*)(&EtS[ch * 128 + jg * 8 + 4]);
            float e0 = ea.x, e1 = ea.y, e2 = ea.z, e3 = ea.w;
            float e4 = eb.x, e5 = eb.y, e6 = eb.z, e7 = eb.w;
#define VQ_ROW(m, zc)                                          \
            acc[m][0] = __builtin_fmaf(zc, e0, acc[m][0]);     \
            acc[m][1] = __builtin_fmaf(zc, e1, acc[m][1]);     \
            acc[m][2] = __builtin_fmaf(zc, e2, acc[m][2]);     \
            acc[m][3] = __builtin_fmaf(zc, e3, acc[m][3]);     \
            acc[m][4] = __builtin_fmaf(zc, e4, acc[m][4]);     \
            acc[m][5] = __builtin_fmaf(zc, e5, acc[m][5]);     \
            acc[m][6] = __builtin_fmaf(zc, e6, acc[m][6]);     \
            acc[m][7] = __builtin_fmaf(zc, e7, acc[m][7]);
            VQ_ROW(0, za.x) VQ_ROW(1, za.y) VQ_ROW(2, za.z) VQ_ROW(3, za.w)
            VQ_ROW(4, zb.x) VQ_ROW(5, zb.y) VQ_ROW(6, zb.z) VQ_ROW(7, zb.w)
#undef VQ_ROW
        }
        if (h == 1) {
            const int qbase = tile * 8;
#pragma unroll
            for (int m = 0; m < 8; ++m)
#pragma unroll
                for (int q = 0; q < 8; ++q) {
                    float A = znm[m] + ekq[q];
                    float d = __builtin_fmaf(-2.0f, acc[m][q], A);
                    if (d < dmin[m]) { dmin[m] = d; qb[m] = qbase + q; }
                }
        }
        __syncthreads();
        if (s + 1 < 16) {
            const int nt = (s + 1) >> 1, nh = (s + 1) & 1;
            const float* src = Etg + nh * 32 * K + nt * 128;
#pragma unroll
            for (int p = 0; p < 4; ++p) {
                int q = wave * 4 + p;
                int c = 2 * q + (lane >> 5);
                const float* gsrc = src + c * K + (lane & 31) * 4;
                __builtin_amdgcn_global_load_lds((gas_ptr)gsrc,
                                                 (las_ptr)&EtS[q * 256], 16, 0, 0);
            }
        }
        __syncthreads();
    }

    u64 bestp[8];
#pragma unroll
    for (int m = 0; m < 8; ++m) {
        int q8 = qb[m];
        int k = ((q8 >> 3) << 7) + jg * 8 + (q8 & 7);
        bestp[m] = packdk(dmin[m], k);
    }
#pragma unroll
    for (int m = 0; m < 8; ++m) {
        u64 v = bestp[m];
#pragma unroll
        for (int mask = 8; mask <= 32; mask <<= 1) {
            u64 o = __shfl_xor(v, mask, 64);
            v = o < v ? o : v;
        }
        bestp[m] = v;
    }
    if (j_l == 0) {
#pragma unroll
        for (int m = 0; m < 8; ++m) red[wave][i_l][m] = bestp[m];
    }
    __syncthreads();
    if (t < MT) {
        int igg = t >> 3, m = t & 7;
        int ihalf = igg >> 3, iw = igg & 7;
        u64 a = red[ihalf][iw][m];
        u64 b2 = red[ihalf + 2][iw][m];
        u64 v = b2 < a ? b2 : a;
        besti[n0 + t] = (int)(v & 0xFFFFFFFFu);
    }
}

// ---------------------------------------------------------------------------
// Kernel 4: gap fallback (R13-verified fb_body, frozen chain).
// ---------------------------------------------------------------------------
__global__ __launch_bounds__(256) void vq_fb_gap(const float* __restrict__ Z,
                                                 const float* __restrict__ Etg,
                                                 const float* __restrict__ ek,
                                                 const int* __restrict__ ulist,
                                                 const int* __restrict__ ucnt,
                                                 int* __restrict__ besti) {
#pragma clang fp contract(off)
    __shared__ float zs[C];
    __shared__ u64 wmin[4];
    const int t = threadIdx.x;
    const int wave = t >> 6, lane = t & 63;
    const int cnt = ucnt[0];
    for (int i = blockIdx.x; i < cnt; i += gridDim.x) {
        const int n = ulist[i];
        const int b = n >> 12, hw = n & 4095;
        __syncthreads();
        if (t < C) zs[t] = Z[b * (C * HW) + t * HW + hw];
        __syncthreads();
        float r[8];
#pragma unroll
        for (int j = 0; j < 8; ++j) r[j] = zs[j] * zs[j];
#pragma unroll
        for (int q = 8; q < C; q += 8)
#pragma unroll
            for (int j = 0; j < 8; ++j) r[j] += zs[q + j] * zs[q + j];
        const float zn = ((r[0] + r[1]) + (r[2] + r[3])) + ((r[4] + r[5]) + (r[6] + r[7]));
        u64 best = ~0ull;
#pragma unroll
        for (int q = 0; q < 4; ++q) {
            const int k = q * 256 + t;
            float a = 0.0f;
#pragma unroll 8
            for (int c = 0; c < C; ++c)
                a = __builtin_fmaf(zs[c], Etg[c * K + k], a);
            float A = zn + ek[k];
            float d = A - 2.0f * a;
            u64 p = packdk(d, k);
            if (p < best) best = p;
        }
#pragma unroll
        for (int m = 1; m <= 32; m <<= 1) {
            u64 o = __shfl_xor(best, m, 64);
            best = o < best ? o : best;
        }
        if (lane == 0) wmin[wave] = best;
        __syncthreads();
        if (t == 0) {
            u64 v = wmin[0];
            if (wmin[1] < v) v = wmin[1];
            if (wmin[2] < v) v = wmin[2];
            if (wmin[3] < v) v = wmin[3];
            besti[n] = (int)(v & 0xFFFFFFFFull);
        }
    }
}

// ---------------------------------------------------------------------------
// Kernel 5/6: epilogue + loss (R13-verified, frozen).
// ---------------------------------------------------------------------------
__global__ __launch_bounds__(256) void vq_epilogue2(const float* __restrict__ Z,
                                                    const float* __restrict__ E,
                                                    const int* __restrict__ besti,
                                                    float* __restrict__ out,
                                                    float* __restrict__ rowloss) {
#pragma clang fp contract(off)
    int n = blockIdx.x * 256 + threadIdx.x;
    int b = n >> 12, hw = n & 4095;
    int best = besti[n];
    const float* zp = Z + b * (C * HW) + hw;
    const float4* eb4 = (const float4*)(E + best * C);
    float* o0 = out + b * (C * HW) + hw;
    float ls = 0.0f;
#pragma unroll
    for (int c4 = 0; c4 < 16; ++c4) {
        float4 e4 = eb4[c4];
        int cb = c4 * 4;
        float z0 = zp[(cb + 0) * HW], z1 = zp[(cb + 1) * HW];
        float z2 = zp[(cb + 2) * HW], z3 = zp[(cb + 3) * HW];
        float f0 = e4.x - z0; o0[(cb + 0) * HW] = z0 + f0; ls += f0 * f0;
        float f1 = e4.y - z1; o0[(cb + 1) * HW] = z1 + f1; ls += f1 * f1;
        float f2 = e4.z - z2; o0[(cb + 2) * HW] = z2 + f2; ls += f2 * f2;
        float f3 = e4.w - z3; o0[(cb + 3) * HW] = z3 + f3; ls += f3 * f3;
    }
    out[OUT0 + n] = (float)best;
    rowloss[n] = ls;
}

__global__ __launch_bounds__(256) void loss2(const float* __restrict__ rowloss,
                                             float* __restrict__ out) {
    __shared__ double sm[256];
    int t = threadIdx.x;
    double s = 0.0;
    for (int i = t; i < N_TOTAL; i += 256) s += (double)rowloss[i];
    sm[t] = s;
    __syncthreads();
    for (int o = 128; o > 0; o >>= 1) {
        if (t < o) sm[t] += sm[t + o];
        __syncthreads();
    }
    if (t == 0) {
        float m = (float)(sm[0] * (1.0 / 8388608.0));
        out[OUT0 + N_TOTAL] = m + 0.25f * m;
    }
}

// ---------------------------------------------------------------------------
// Small-ws fallback path (R2-proven, frozen).
// ---------------------------------------------------------------------------
__global__ __launch_bounds__(256) void ek_kernel(const float* __restrict__ E,
                                                 float* __restrict__ ek) {
#pragma clang fp contract(off)
    int k = blockIdx.x * 256 + threadIdx.x;
    if (k >= K) return;
    const float* e = E + k * C;
    float r[8];
#pragma unroll
    for (int j = 0; j < 8; ++j) { float v = e[j]; r[j] = v * v; }
#pragma unroll
    for (int i = 8; i < C; i += 8)
#pragma unroll
        for (int j = 0; j < 8; ++j) { float v = e[i + j]; r[j] += v * v; }
    ek[k] = ((r[0] + r[1]) + (r[2] + r[3])) + ((r[4] + r[5]) + (r[6] + r[7]));
}

__global__ __launch_bounds__(256, 4) void vq_combined(const float* __restrict__ Z,
                                                      const float* __restrict__ E,
                                                      const float* __restrict__ ek,
                                                      float* __restrict__ out,
                                                      float* __restrict__ partials) {
#pragma clang fp contract(off)
    int n = blockIdx.x * 256 + threadIdx.x;
    int b = n >> 12, hw = n & 4095;
    const float* zp = Z + b * (C * HW) + hw;
    float z[C];
#pragma unroll
    for (int c = 0; c < C; ++c) z[c] = zp[c * HW];
    float zn;
    {
        float r[8];
#pragma unroll
        for (int j = 0; j < 8; ++j) r[j] = z[j] * z[j];
#pragma unroll
        for (int i = 8; i < C; i += 8)
#pragma unroll
            for (int j = 0; j < 8; ++j) r[j] += z[i + j] * z[i + j];
        zn = ((r[0] + r[1]) + (r[2] + r[3])) + ((r[4] + r[5]) + (r[6] + r[7]));
    }
    float dmin = __builtin_inff();
    int best = 0;
#pragma unroll 1
    for (int k = 0; k < K; k += 4) {
        const float* e0 = E + k * C;
        float a0 = 0.0f, a1 = 0.0f, a2 = 0.0f, a3 = 0.0f;
#pragma unroll
        for (int c = 0; c < C; ++c) {
            float zc = z[c];
            a0 = __builtin_fmaf(zc, e0[c], a0);
            a1 = __builtin_fmaf(zc, e0[C + c], a1);
            a2 = __builtin_fmaf(zc, e0[2 * C + c], a2);
            a3 = __builtin_fmaf(zc, e0[3 * C + c], a3);
        }
        float A0 = zn + ek[k],     A1 = zn + ek[k + 1];
        float A2 = zn + ek[k + 2], A3 = zn + ek[k + 3];
        float d0 = A0 - 2.0f * a0, d1 = A1 - 2.0f * a1;
        float d2 = A2 - 2.0f * a2, d3 = A3 - 2.0f * a3;
        if (d0 < dmin) { dmin = d0; best = k; }
        if (d1 < dmin) { dmin = d1; best = k + 1; }
        if (d2 < dmin) { dmin = d2; best = k + 2; }
        if (d3 < dmin) { dmin = d3; best = k + 3; }
    }
    const float4* eb4 = (const float4*)(E + best * C);
    float* o0 = out + b * (C * HW) + hw;
    float ls = 0.0f;
#pragma unroll
    for (int c4 = 0; c4 < 16; ++c4) {
        float4 e4 = eb4[c4];
        int cb = c4 * 4;
        float f0 = e4.x - z[cb + 0]; o0[(cb + 0) * HW] = z[cb + 0] + f0; ls += f0 * f0;
        float f1 = e4.y - z[cb + 1]; o0[(cb + 1) * HW] = z[cb + 1] + f1; ls += f1 * f1;
        float f2 = e4.z - z[cb + 2]; o0[(cb + 2) * HW] = z[cb + 2] + f2; ls += f2 * f2;
        float f3 = e4.w - z[cb + 3]; o0[(cb + 3) * HW] = z[cb + 3] + f3; ls += f3 * f3;
    }
    out[OUT0 + n] = (float)best;
#pragma unroll
    for (int off = 32; off > 0; off >>= 1) ls += __shfl_xor(ls, off, 64);
    if ((threadIdx.x & 63) == 0) partials[n >> 6] = ls;
}

__global__ __launch_bounds__(256) void loss_kernel(const float* __restrict__ partials,
                                                   float* __restrict__ out) {
    __shared__ double sm[256];
    int t = threadIdx.x;
    double s = 0.0;
    for (int i = t; i < (N_TOTAL / 64); i += 256) s += (double)partials[i];
    sm[t] = s;
    __syncthreads();
    for (int o = 128; o > 0; o >>= 1) {
        if (t < o) sm[t] += sm[t + o];
        __syncthreads();
    }
    if (t == 0) {
        float m = (float)(sm[0] * (1.0 / 8388608.0));
        out[OUT0 + N_TOTAL] = m + 0.25f * m;
    }
}

extern "C" void kernel_launch(void* const* d_in, const int* in_sizes, int n_in,
                              void* d_out, int out_size, void* d_ws, size_t ws_size,
                              hipStream_t stream) {
    const float* Z = (const float*)d_in[0];
    const float* E = (const float*)d_in[1];
    float* out = (float*)d_out;
    float* ws = (float*)d_ws;
    float* ek = ws + WS_EK;

    if (ws_size >= (size_t)WS_NEED2 * sizeof(float)) {
        int* besti   = (int*)(ws + WS_BESTI);
        int* ulistB  = (int*)(ws + WS_ULISTB);
        int* ucnt    = (int*)(ws + WS_UCNT);
        int* bflag   = (int*)(ws + WS_BFLAG);
        short* EbfS  = (short*)(ws + WS_EBF);
        float* Etg   = ws + WS_ETG;
        float* rowloss = ws + WS_ROWLOSS;

        hipLaunchKernelGGL(eprep2, dim3(K / 256), dim3(256), 0, stream,
                           E, ek, EbfS, Etg, ucnt);
        hipLaunchKernelGGL(vq_mfma, dim3(N_TOTAL / MT), dim3(256), 0, stream,
                           Z, E, ek, EbfS, besti, ulistB, ucnt, bflag);
        hipLaunchKernelGGL(vq_exact_block, dim3(N_TOTAL / MT), dim3(256), 0, stream,
                           Z, Etg, ek, bflag, besti);
        hipLaunchKernelGGL(vq_fb_gap, dim3(2048), dim3(256), 0, stream,
                           Z, Etg, ek, ulistB, ucnt, besti);
        hipLaunchKernelGGL(vq_epilogue2, dim3(N_TOTAL / 256), dim3(256), 0, stream,
                           Z, E, besti, out, rowloss);
        hipLaunchKernelGGL(loss2, dim3(1), dim3(256), 0, stream, rowloss, out);
    } else {
        float* partials = ws + 1024;
        hipLaunchKernelGGL(ek_kernel, dim3(4), dim3(256), 0, stream, E, ek);
        hipLaunchKernelGGL(vq_combined, dim3(N_TOTAL / 256), dim3(256), 0, stream,
                           Z, E, ek, out, partials);
        hipLaunchKernelGGL(loss_kernel, dim3(1), dim3(256), 0, stream, partials, out);
    }
}

// Round 15
// 473.313 us; speedup vs baseline: 1.5920x; 1.1828x over previous
//
#include <hip/hip_runtime.h>

#define C 64
#define K 1024
#define HW 4096
#define N_TOTAL 131072   // 32*64*64
#define OUT0 8388608     // 32*64*64*64 (z_q_out elements)
#define MT 128           // n-rows per block
#define KT2 64           // codes per MFMA k-tile
#define NT2 16

#define GAP_THR 1.5e-4f  // certainty margin (differential rounding <= ~5e-5)
#define CHK_THR 1e-4f    // calibration threshold (|S-a|~2e-5 right, ~6e-3 wrong)

// d_ws float offsets (R14-verified map). 526352 f = 2.105 MB.
#define WS_EK        0         // 1024 f
#define WS_BESTI     1024      // 131072 int
#define WS_ULISTB    132096    // 131072 int (gap rows)
#define WS_UCNT      263168    // 16 int
#define WS_BFLAG     263184    // 1024 int
#define WS_EBF       264208    // 65536 f = 262144 B bf16 chunks
#define WS_ETG       329744    // 65536 f
#define WS_ROWLOSS   395280    // 131072 f
#define WS_NEED2     526352

typedef unsigned int u32;
typedef unsigned long long u64;
typedef __attribute__((ext_vector_type(8))) short short8;
typedef __attribute__((ext_vector_type(4))) float f32x4;
typedef const __attribute__((address_space(1))) void* gas_ptr;
typedef __attribute__((address_space(3))) void* las_ptr;

__device__ __forceinline__ u64 packdk(float d, int k) {
    u32 b = __float_as_uint(d);
    u32 m = b ^ ((u32)((int)b >> 31) | 0x80000000u);
    return ((u64)m << 32) | (u32)k;
}
__device__ __forceinline__ unsigned short f2bf(float x) {
    u32 u = __float_as_uint(x);
    return (unsigned short)((u + 0x7FFFu + ((u >> 16) & 1u)) >> 16);
}
__device__ __forceinline__ float bf2f(unsigned short h) {
    u32 u = ((u32)h) << 16;
    return __uint_as_float(u);
}

// ---------------------------------------------------------------------------
// Kernel 1: E prep (R14-verified verbatim).
// ---------------------------------------------------------------------------
__global__ __launch_bounds__(256) void eprep2(const float* __restrict__ E,
                                              float* __restrict__ ek,
                                              short* __restrict__ EbfS,
                                              float* __restrict__ Etg,
                                              int* __restrict__ ucnt) {
#pragma clang fp contract(off)
    if (blockIdx.x == 0 && threadIdx.x < 2) ucnt[threadIdx.x] = 0;
    int k = blockIdx.x * 256 + threadIdx.x;
    const float* e = E + k * C;
    float ev[C];
#pragma unroll
    for (int c4 = 0; c4 < 16; ++c4) {
        float4 v = *(const float4*)(e + c4 * 4);
        ev[c4 * 4 + 0] = v.x; ev[c4 * 4 + 1] = v.y;
        ev[c4 * 4 + 2] = v.z; ev[c4 * 4 + 3] = v.w;
    }
    float r[8];
#pragma unroll
    for (int j = 0; j < 8; ++j) r[j] = ev[j] * ev[j];
#pragma unroll
    for (int i = 8; i < C; i += 8)
#pragma unroll
        for (int j = 0; j < 8; ++j) r[j] += ev[i + j] * ev[i + j];
    ek[k] = ((r[0] + r[1]) + (r[2] + r[3])) + ((r[4] + r[5]) + (r[6] + r[7]));
#pragma unroll
    for (int c = 0; c < C; ++c) Etg[c * K + k] = ev[c];

    unsigned short hi[C], lo[C];
#pragma unroll
    for (int c = 0; c < C; ++c) {
        unsigned short h = f2bf(ev[c]);
        hi[c] = h;
        lo[c] = f2bf(ev[c] - bf2f(h));
    }
#pragma unroll
    for (int ci = 0; ci < 16; ++ci) {
        int p = ci >> 3, c0 = (ci & 7) * 8;
        short8 v;
#pragma unroll
        for (int e2 = 0; e2 < 8; ++e2)
            v[e2] = (short)(p ? lo[c0 + e2] : hi[c0 + e2]);
        int slot = k * 16 + (ci ^ (k & 7));
        *(short8*)&EbfS[slot * 8] = v;
    }
}

// ---------------------------------------------------------------------------
// Kernel 2: MFMA argmin, R15 restructure of the R14-verified kernel:
//  - calibration trimmed to 2 discriminating dots/lane (was 16): I1's acc[0]
//    = dot(row wr+gidx*4, code m15), I2's acc[0] = dot(row wr+m15, code
//    gidx*4). Per-block vote w/ __all; no match -> bflag -> exact redo.
//  - E-tiles DOUBLE-BUFFERED (2x16KB in SA): one barrier per tile; barrier's
//    vmcnt-drain covers a DMA issued a full tile earlier (latency hidden).
//  - d-updates, mode-branched decode, gap list, integrity check: R14 verbatim.
// ---------------------------------------------------------------------------
__global__ __launch_bounds__(256, 2) void vq_mfma(const float* __restrict__ Z,
                                                  const float* __restrict__ Efp,
                                                  const float* __restrict__ ek,
                                                  const short* __restrict__ EbfS,
                                                  int* __restrict__ besti,
                                                  int* __restrict__ ulistB,
                                                  int* __restrict__ ucnt,
                                                  int* __restrict__ bflag) {
#pragma clang fp contract(off)
    __shared__ float SA[8192];             // phase1: ZtF fp32; then 2x16KB E-tile bufs
    __shared__ unsigned short Zb[16384];   // split-bf16 A planes (swizzled)
    __shared__ int vmode[4];
    __shared__ int anyBad;

    const int t = threadIdx.x;
    const int wave = t >> 6, lane = t & 63;
    const int gidx = lane >> 4;
    const int m15 = lane & 15;
    const int wr = wave * 32;
    const int n0 = blockIdx.x * MT;
    const int b = n0 >> 12;
    const int hw0 = n0 & 4095;
    const float* zbase = Z + b * (C * HW) + hw0;
    if (t == 0) anyBad = 0;

    // ---- stage ZtF fp32 [c][n] (coalesced) ----
#pragma unroll
    for (int r = 0; r < 8; ++r) {
        int idx4 = r * 256 + t;
        int c = idx4 >> 5, n4 = idx4 & 31;
        float4 v = *(const float4*)(zbase + c * HW + n4 * 4);
        *(float4*)(&SA[c * MT + n4 * 4]) = v;
    }
    __syncthreads();

    // ---- 2 discriminating check dots (frozen seq-fma) ----
    float chk1 = 0.0f, chk2 = 0.0f;
    {
        const float* eI1 = Efp + m15 * C;
        const float* eI2 = Efp + (gidx * 4) * C;
#pragma unroll 8
        for (int c = 0; c < C; ++c) {
            chk1 = __builtin_fmaf(SA[c * MT + wr + gidx * 4], eI1[c], chk1);
            chk2 = __builtin_fmaf(SA[c * MT + wr + m15],      eI2[c], chk2);
        }
    }
    // ---- convert Z to split-bf16 planes, Zb chunk slot = c8 ^ (row&7) ----
    {
        int r = t & 127, p = t >> 7;
#pragma unroll
        for (int c8 = 0; c8 < 8; ++c8) {
            short8 v;
#pragma unroll
            for (int e2 = 0; e2 < 8; ++e2) {
                float z = SA[(c8 * 8 + e2) * MT + r];
                unsigned short h = f2bf(z);
                v[e2] = (short)(p ? f2bf(z - bf2f(h)) : h);
            }
            int slot = c8 ^ (r & 7);
            *(short8*)&Zb[r * 128 + p * 64 + slot * 8] = v;
        }
    }
    __syncthreads();

    // ---- A fragments (swizzled read) ----
    short8 af[2][2][2];
#pragma unroll
    for (int rt = 0; rt < 2; ++rt)
#pragma unroll
        for (int ks = 0; ks < 2; ++ks)
#pragma unroll
            for (int p = 0; p < 2; ++p) {
                int row = wr + rt * 16 + m15;
                int slot = (ks * 4 + gidx) ^ (m15 & 7);
                af[rt][ks][p] = *(const short8*)&Zb[row * 128 + p * 64 + slot * 8];
            }

    // ---- DMA tiles 0,1 into buf0,buf1 ----
#define ISSUE_TILE(tauv, bufsel)                                              \
    {                                                                         \
        _Pragma("unroll")                                                     \
        for (int p2 = 0; p2 < 4; ++p2) {                                      \
            int q = wave * 4 + p2;                                            \
            const char* gsrc = (const char*)EbfS + (tauv) * 16384 + q * 1024 + lane * 16; \
            __builtin_amdgcn_global_load_lds((gas_ptr)gsrc,                   \
                (las_ptr)((char*)SA + (bufsel) * 16384 + q * 1024), 16, 0, 0);\
        }                                                                     \
    }
    ISSUE_TILE(0, 0)
    ISSUE_TILE(1, 1)
    __syncthreads();   // vmcnt drain: tiles 0,1 ready

#define LOAD_BF(bf_, cgv, basec)                                            \
    {                                                                       \
        int kl_ = (cgv) * 16 + m15;                                         \
        _Pragma("unroll")                                                   \
        for (int ks = 0; ks < 2; ++ks)                                      \
            _Pragma("unroll")                                               \
            for (int p = 0; p < 2; ++p) {                                   \
                int ci = p * 8 + ks * 4 + gidx;                             \
                int sca = kl_ * 16 + (ci ^ (m15 & 7));                      \
                bf_[ks][p] = *(const short8*)((basec) + sca * 16);          \
            }                                                               \
    }
#define MFMA6(acc, rt, bf_)                                                          \
    acc = __builtin_amdgcn_mfma_f32_16x16x32_bf16(af[rt][0][0], bf_[0][0], acc, 0, 0, 0); \
    acc = __builtin_amdgcn_mfma_f32_16x16x32_bf16(af[rt][0][0], bf_[0][1], acc, 0, 0, 0); \
    acc = __builtin_amdgcn_mfma_f32_16x16x32_bf16(af[rt][0][1], bf_[0][0], acc, 0, 0, 0); \
    acc = __builtin_amdgcn_mfma_f32_16x16x32_bf16(af[rt][1][0], bf_[1][0], acc, 0, 0, 0); \
    acc = __builtin_amdgcn_mfma_f32_16x16x32_bf16(af[rt][1][0], bf_[1][1], acc, 0, 0, 0); \
    acc = __builtin_amdgcn_mfma_f32_16x16x32_bf16(af[rt][1][1], bf_[1][0], acc, 0, 0, 0);

    // ---- calibrate on (tile0, cg0, rt0): acc[0] vs the two hypotheses ----
    {
        short8 bf_[2][2];
        LOAD_BF(bf_, 0, (const char*)SA);
        f32x4 acc = {0.0f, 0.0f, 0.0f, 0.0f};
        MFMA6(acc, 0, bf_);
        int ok1 = (__builtin_fabsf(acc[0] - chk1) < CHK_THR) ? 1 : 0;
        int ok2 = (__builtin_fabsf(acc[0] - chk2) < CHK_THR) ? 1 : 0;
        int a1 = __all(ok1), a2 = __all(ok2);
        if (lane == 0) vmode[wave] = a1 ? 1 : (a2 ? 2 : 0);
    }
    __syncthreads();
    int mode = vmode[0];
    if (vmode[1] != mode || vmode[2] != mode || vmode[3] != mode) mode = 0;
    if (mode == 0) {
        if (t == 0) bflag[blockIdx.x] = 1;
        return;
    }

    float d1f[8], d2f[8];
    int kb[8];
#pragma unroll
    for (int s = 0; s < 8; ++s) { d1f[s] = __builtin_inff(); d2f[s] = __builtin_inff(); kb[s] = 0; }

#pragma unroll 1
    for (int tau = 0; tau < NT2; ++tau) {
        const char* bufc = (const char*)SA + (tau & 1) * 16384;
#pragma unroll 1
        for (int cg = 0; cg < 4; ++cg) {
            const int base = tau * 64 + cg * 16;
            float ekvS[8];
            if (mode == 1) {
                float v = ek[base + m15];
#pragma unroll
                for (int s = 0; s < 8; ++s) ekvS[s] = v;
            } else {
                float e0 = ek[base + gidx * 4 + 0];
                float e1 = ek[base + gidx * 4 + 1];
                float e2 = ek[base + gidx * 4 + 2];
                float e3 = ek[base + gidx * 4 + 3];
                ekvS[0] = e0; ekvS[1] = e1; ekvS[2] = e2; ekvS[3] = e3;
                ekvS[4] = e0; ekvS[5] = e1; ekvS[6] = e2; ekvS[7] = e3;
            }
            short8 bf_[2][2];
            LOAD_BF(bf_, cg, bufc);
#pragma unroll
            for (int rt = 0; rt < 2; ++rt) {
                f32x4 acc = {0.0f, 0.0f, 0.0f, 0.0f};
                MFMA6(acc, rt, bf_);
#pragma unroll
                for (int j = 0; j < 4; ++j) {
                    int s = rt * 4 + j;
                    float d = __builtin_fmaf(-2.0f, acc[j], ekvS[s]);
                    if (d < d1f[s]) { d2f[s] = d1f[s]; d1f[s] = d; kb[s] = base; }
                    else if (d < d2f[s]) { d2f[s] = d; }
                }
            }
        }
        __syncthreads();   // drains DMA(tau+1) issued last iter; frees buf[tau&1]
        if (tau + 2 < NT2) ISSUE_TILE(tau + 2, tau & 1)
    }

    // ---- staged-data integrity check on tile 15 (in buf1, mode-independent) ----
    {
        const char* bufc = (const char*)SA + ((NT2 - 1) & 1) * 16384;
        int kl = m15;
        int kg = (NT2 - 1) * 64 + kl;
        int bad = 0;
#pragma unroll
        for (int pair = 0; pair < 2; ++pair) {
            int ks = pair, p = pair;
            int ci = p * 8 + ks * 4 + gidx;
            int sca = kl * 16 + (ci ^ (m15 & 7));
            short8 got = *(const short8*)(bufc + sca * 16);
#pragma unroll
            for (int j = 0; j < 8; ++j) {
                int c = ks * 32 + gidx * 8 + j;
                float evv = Efp[kg * C + c];
                unsigned short h = f2bf(evv);
                unsigned short want = p ? f2bf(evv - bf2f(h)) : h;
                bad |= ((unsigned short)got[j] != want) ? 1 : 0;
            }
        }
        if (bad) anyBad = 1;
    }
    __syncthreads();
    int flag = anyBad;
    if (t == 0) bflag[blockIdx.x] = flag ? 1 : 0;
    if (flag) return;

    // ---- decode + reduce + write, per mode (R14-verified verbatim) ----
    if (mode == 1) {
#pragma unroll
        for (int s = 0; s < 8; ++s) {
            u64 v = packdk(d1f[s], kb[s] + m15);
            float d1 = d1f[s], d2 = d2f[s];
#pragma unroll
            for (int mask = 1; mask <= 8; mask <<= 1) {
                u64 po = __shfl_xor(v, mask, 64);
                float d1o = __shfl_xor(d1, mask, 64);
                float d2o = __shfl_xor(d2, mask, 64);
                d2 = fminf(fminf(d2, d2o), fmaxf(d1, d1o));
                d1 = fminf(d1, d1o);
                if (po < v) v = po;
            }
            if (m15 == 0) {
                int n = n0 + wr + (s >> 2) * 16 + gidx * 4 + (s & 3);
                besti[n] = (int)(v & 0xFFFFFFFFu);
                if (!((d2 - d1) > GAP_THR)) {
                    int ix = atomicAdd(&ucnt[0], 1);
                    ulistB[ix] = n;
                }
            }
        }
    } else {
#pragma unroll
        for (int rt = 0; rt < 2; ++rt) {
            int s0 = rt * 4;
            u64 v = packdk(d1f[s0], kb[s0] + gidx * 4 + 0);
            float d1 = d1f[s0], d2 = d2f[s0];
#pragma unroll
            for (int j = 1; j < 4; ++j) {
                int s = s0 + j;
                u64 po = packdk(d1f[s], kb[s] + gidx * 4 + j);
                float d1o = d1f[s], d2o = d2f[s];
                d2 = fminf(fminf(d2, d2o), fmaxf(d1, d1o));
                d1 = fminf(d1, d1o);
                if (po < v) v = po;
            }
#pragma unroll
            for (int mask = 16; mask <= 32; mask <<= 1) {
                u64 po = __shfl_xor(v, mask, 64);
                float d1o = __shfl_xor(d1, mask, 64);
                float d2o = __shfl_xor(d2, mask, 64);
                d2 = fminf(fminf(d2, d2o), fmaxf(d1, d1o));
                d1 = fminf(d1, d1o);
                if (po < v) v = po;
            }
            if (gidx == 0) {
                int n = n0 + wr + rt * 16 + m15;
                besti[n] = (int)(v & 0xFFFFFFFFu);
                if (!((d2 - d1) > GAP_THR)) {
                    int ix = atomicAdd(&ucnt[0], 1);
                    ulistB[ix] = n;
                }
            }
        }
    }
#undef LOAD_BF
#undef MFMA6
#undef ISSUE_TILE
}

// ---------------------------------------------------------------------------
// Kernel 3: R10-proven exact GEMM, gated per flagged block (R14 verbatim).
// ---------------------------------------------------------------------------
__global__ __launch_bounds__(256, 2) void vq_exact_block(const float* __restrict__ Z,
                                                         const float* __restrict__ Etg,
                                                         const float* __restrict__ ek,
                                                         const int* __restrict__ bflag,
                                                         int* __restrict__ besti) {
#pragma clang fp contract(off)
    if (bflag[blockIdx.x] == 0) return;
    __shared__ float Zt[C * MT];
    __shared__ float EtS[32 * 128];
    __shared__ float znbuf[MT];
    __shared__ u64 red[4][8][8];

    const int t = threadIdx.x;
    const int wave = t >> 6, lane = t & 63;
    const int n0 = blockIdx.x * MT;
    const int b = n0 >> 12;
    const int hw0 = n0 & 4095;
    const float* zbase = Z + b * (C * HW) + hw0;

#pragma unroll
    for (int r = 0; r < 8; ++r) {
        int idx4 = r * 256 + t;
        int c = idx4 >> 5, n4 = idx4 & 31;
        float4 v = *(const float4*)(zbase + c * HW + n4 * 4);
        *(float4*)(&Zt[c * MT + n4 * 4]) = v;
    }
#pragma unroll
    for (int p = 0; p < 4; ++p) {
        int q = wave * 4 + p;
        int c = 2 * q + (lane >> 5);
        const float* gsrc = Etg + c * K + (lane & 31) * 4;
        __builtin_amdgcn_global_load_lds((gas_ptr)gsrc, (las_ptr)&EtS[q * 256],
                                         16, 0, 0);
    }
    __syncthreads();

    if (t < MT) {
        float r8[8];
#pragma unroll
        for (int j = 0; j < 8; ++j) { float v = Zt[j * MT + t]; r8[j] = v * v; }
#pragma unroll
        for (int i = 1; i < 8; ++i)
#pragma unroll
            for (int j = 0; j < 8; ++j) { float v = Zt[(i * 8 + j) * MT + t]; r8[j] += v * v; }
        znbuf[t] = ((r8[0] + r8[1]) + (r8[2] + r8[3])) + ((r8[4] + r8[5]) + (r8[6] + r8[7]));
    }
    __syncthreads();

    const int i_l = lane & 7, j_l = lane >> 3;
    const int ig = ((wave & 1) << 3) | i_l;
    const int jg = ((wave >> 1) << 3) | j_l;

    float znm[8];
#pragma unroll
    for (int m = 0; m < 8; ++m) znm[m] = znbuf[ig * 8 + m];

    float dmin[8];
    int qb[8];
#pragma unroll
    for (int m = 0; m < 8; ++m) { dmin[m] = __builtin_inff(); qb[m] = 0; }

    float acc[8][8];
    float ekq[8];

#pragma unroll 1
    for (int s = 0; s < 16; ++s) {
        const int tile = s >> 1;
        const int h = s & 1;
        if (h == 0) {
            const float* ekp = ek + tile * 128 + jg * 8;
            float4 a = *(const float4*)ekp;
            float4 bq = *(const float4*)(ekp + 4);
            ekq[0] = a.x;  ekq[1] = a.y;  ekq[2] = a.z;  ekq[3] = a.w;
            ekq[4] = bq.x; ekq[5] = bq.y; ekq[6] = bq.z; ekq[7] = bq.w;
#pragma unroll
            for (int m = 0; m < 8; ++m)
#pragma unroll
                for (int q = 0; q < 8; ++q) acc[m][q] = 0.0f;
        }
        const int cbase = h * 32;
#pragma unroll 4
        for (int ch = 0; ch < 32; ++ch) {
            int c = cbase + ch;
            float4 za = *(const float4*)(&Zt[c * MT + ig * 8]);
            float4 zb = *(const float4*)(&Zt[c * MT + ig * 8 + 4]);
            float4 ea = *(const float4*)(&EtS[ch * 128 + jg * 8]);
            float4 eb = *(const float4*)(&EtS[ch * 128 + jg * 8 + 4]);
            float e0 = ea.x, e1 = ea.y, e2 = ea.z, e3 = ea.w;
            float e4 = eb.x, e5 = eb.y, e6 = eb.z, e7 = eb.w;
#define VQ_ROW(m, zc)                                          \
            acc[m][0] = __builtin_fmaf(zc, e0, acc[m][0]);     \
            acc[m][1] = __builtin_fmaf(zc, e1, acc[m][1]);     \
            acc[m][2] = __builtin_fmaf(zc, e2, acc[m][2]);     \
            acc[m][3] = __builtin_fmaf(zc, e3, acc[m][3]);     \
            acc[m][4] = __builtin_fmaf(zc, e4, acc[m][4]);     \
            acc[m][5] = __builtin_fmaf(zc, e5, acc[m][5]);     \
            acc[m][6] = __builtin_fmaf(zc, e6, acc[m][6]);     \
            acc[m][7] = __builtin_fmaf(zc, e7, acc[m][7]);
            VQ_ROW(0, za.x) VQ_ROW(1, za.y) VQ_ROW(2, za.z) VQ_ROW(3, za.w)
            VQ_ROW(4, zb.x) VQ_ROW(5, zb.y) VQ_ROW(6, zb.z) VQ_ROW(7, zb.w)
#undef VQ_ROW
        }
        if (h == 1) {
            const int qbase = tile * 8;
#pragma unroll
            for (int m = 0; m < 8; ++m)
#pragma unroll
                for (int q = 0; q < 8; ++q) {
                    float A = znm[m] + ekq[q];
                    float d = __builtin_fmaf(-2.0f, acc[m][q], A);
                    if (d < dmin[m]) { dmin[m] = d; qb[m] = qbase + q; }
                }
        }
        __syncthreads();
        if (s + 1 < 16) {
            const int nt = (s + 1) >> 1, nh = (s + 1) & 1;
            const float* src = Etg + nh * 32 * K + nt * 128;
#pragma unroll
            for (int p = 0; p < 4; ++p) {
                int q = wave * 4 + p;
                int c = 2 * q + (lane >> 5);
                const float* gsrc = src + c * K + (lane & 31) * 4;
                __builtin_amdgcn_global_load_lds((gas_ptr)gsrc,
                                                 (las_ptr)&EtS[q * 256], 16, 0, 0);
            }
        }
        __syncthreads();
    }

    u64 bestp[8];
#pragma unroll
    for (int m = 0; m < 8; ++m) {
        int q8 = qb[m];
        int k = ((q8 >> 3) << 7) + jg * 8 + (q8 & 7);
        bestp[m] = packdk(dmin[m], k);
    }
#pragma unroll
    for (int m = 0; m < 8; ++m) {
        u64 v = bestp[m];
#pragma unroll
        for (int mask = 8; mask <= 32; mask <<= 1) {
            u64 o = __shfl_xor(v, mask, 64);
            v = o < v ? o : v;
        }
        bestp[m] = v;
    }
    if (j_l == 0) {
#pragma unroll
        for (int m = 0; m < 8; ++m) red[wave][i_l][m] = bestp[m];
    }
    __syncthreads();
    if (t < MT) {
        int igg = t >> 3, m = t & 7;
        int ihalf = igg >> 3, iw = igg & 7;
        u64 a = red[ihalf][iw][m];
        u64 b2 = red[ihalf + 2][iw][m];
        u64 v = b2 < a ? b2 : a;
        besti[n0 + t] = (int)(v & 0xFFFFFFFFu);
    }
}

// ---------------------------------------------------------------------------
// Kernel 4: gap fallback (R14 verbatim, frozen chain).
// ---------------------------------------------------------------------------
__global__ __launch_bounds__(256) void vq_fb_gap(const float* __restrict__ Z,
                                                 const float* __restrict__ Etg,
                                                 const float* __restrict__ ek,
                                                 const int* __restrict__ ulist,
                                                 const int* __restrict__ ucnt,
                                                 int* __restrict__ besti) {
#pragma clang fp contract(off)
    __shared__ float zs[C];
    __shared__ u64 wmin[4];
    const int t = threadIdx.x;
    const int wave = t >> 6, lane = t & 63;
    const int cnt = ucnt[0];
    for (int i = blockIdx.x; i < cnt; i += gridDim.x) {
        const int n = ulist[i];
        const int b = n >> 12, hw = n & 4095;
        __syncthreads();
        if (t < C) zs[t] = Z[b * (C * HW) + t * HW + hw];
        __syncthreads();
        float r[8];
#pragma unroll
        for (int j = 0; j < 8; ++j) r[j] = zs[j] * zs[j];
#pragma unroll
        for (int q = 8; q < C; q += 8)
#pragma unroll
            for (int j = 0; j < 8; ++j) r[j] += zs[q + j] * zs[q + j];
        const float zn = ((r[0] + r[1]) + (r[2] + r[3])) + ((r[4] + r[5]) + (r[6] + r[7]));
        u64 best = ~0ull;
#pragma unroll
        for (int q = 0; q < 4; ++q) {
            const int k = q * 256 + t;
            float a = 0.0f;
#pragma unroll 8
            for (int c = 0; c < C; ++c)
                a = __builtin_fmaf(zs[c], Etg[c * K + k], a);
            float A = zn + ek[k];
            float d = A - 2.0f * a;
            u64 p = packdk(d, k);
            if (p < best) best = p;
        }
#pragma unroll
        for (int m = 1; m <= 32; m <<= 1) {
            u64 o = __shfl_xor(best, m, 64);
            best = o < best ? o : best;
        }
        if (lane == 0) wmin[wave] = best;
        __syncthreads();
        if (t == 0) {
            u64 v = wmin[0];
            if (wmin[1] < v) v = wmin[1];
            if (wmin[2] < v) v = wmin[2];
            if (wmin[3] < v) v = wmin[3];
            besti[n] = (int)(v & 0xFFFFFFFFull);
        }
    }
}

// ---------------------------------------------------------------------------
// Kernel 5/6: epilogue + loss (R14 verbatim, frozen).
// ---------------------------------------------------------------------------
__global__ __launch_bounds__(256) void vq_epilogue2(const float* __restrict__ Z,
                                                    const float* __restrict__ E,
                                                    const int* __restrict__ besti,
                                                    float* __restrict__ out,
                                                    float* __restrict__ rowloss) {
#pragma clang fp contract(off)
    int n = blockIdx.x * 256 + threadIdx.x;
    int b = n >> 12, hw = n & 4095;
    int best = besti[n];
    const float* zp = Z + b * (C * HW) + hw;
    const float4* eb4 = (const float4*)(E + best * C);
    float* o0 = out + b * (C * HW) + hw;
    float ls = 0.0f;
#pragma unroll
    for (int c4 = 0; c4 < 16; ++c4) {
        float4 e4 = eb4[c4];
        int cb = c4 * 4;
        float z0 = zp[(cb + 0) * HW], z1 = zp[(cb + 1) * HW];
        float z2 = zp[(cb + 2) * HW], z3 = zp[(cb + 3) * HW];
        float f0 = e4.x - z0; o0[(cb + 0) * HW] = z0 + f0; ls += f0 * f0;
        float f1 = e4.y - z1; o0[(cb + 1) * HW] = z1 + f1; ls += f1 * f1;
        float f2 = e4.z - z2; o0[(cb + 2) * HW] = z2 + f2; ls += f2 * f2;
        float f3 = e4.w - z3; o0[(cb + 3) * HW] = z3 + f3; ls += f3 * f3;
    }
    out[OUT0 + n] = (float)best;
    rowloss[n] = ls;
}

__global__ __launch_bounds__(256) void loss2(const float* __restrict__ rowloss,
                                             float* __restrict__ out) {
    __shared__ double sm[256];
    int t = threadIdx.x;
    double s = 0.0;
    for (int i = t; i < N_TOTAL; i += 256) s += (double)rowloss[i];
    sm[t] = s;
    __syncthreads();
    for (int o = 128; o > 0; o >>= 1) {
        if (t < o) sm[t] += sm[t + o];
        __syncthreads();
    }
    if (t == 0) {
        float m = (float)(sm[0] * (1.0 / 8388608.0));
        out[OUT0 + N_TOTAL] = m + 0.25f * m;
    }
}

// ---------------------------------------------------------------------------
// Small-ws fallback path (R2-proven, frozen).
// ---------------------------------------------------------------------------
__global__ __launch_bounds__(256) void ek_kernel(const float* __restrict__ E,
                                                 float* __restrict__ ek) {
#pragma clang fp contract(off)
    int k = blockIdx.x * 256 + threadIdx.x;
    if (k >= K) return;
    const float* e = E + k * C;
    float r[8];
#pragma unroll
    for (int j = 0; j < 8; ++j) { float v = e[j]; r[j] = v * v; }
#pragma unroll
    for (int i = 8; i < C; i += 8)
#pragma unroll
        for (int j = 0; j < 8; ++j) { float v = e[i + j]; r[j] += v * v; }
    ek[k] = ((r[0] + r[1]) + (r[2] + r[3])) + ((r[4] + r[5]) + (r[6] + r[7]));
}

__global__ __launch_bounds__(256, 4) void vq_combined(const float* __restrict__ Z,
                                                      const float* __restrict__ E,
                                                      const float* __restrict__ ek,
                                                      float* __restrict__ out,
                                                      float* __restrict__ partials) {
#pragma clang fp contract(off)
    int n = blockIdx.x * 256 + threadIdx.x;
    int b = n >> 12, hw = n & 4095;
    const float* zp = Z + b * (C * HW) + hw;
    float z[C];
#pragma unroll
    for (int c = 0; c < C; ++c) z[c] = zp[c * HW];
    float zn;
    {
        float r[8];
#pragma unroll
        for (int j = 0; j < 8; ++j) r[j] = z[j] * z[j];
#pragma unroll
        for (int i = 8; i < C; i += 8)
#pragma unroll
            for (int j = 0; j < 8; ++j) r[j] += z[i + j] * z[i + j];
        zn = ((r[0] + r[1]) + (r[2] + r[3])) + ((r[4] + r[5]) + (r[6] + r[7]));
    }
    float dmin = __builtin_inff();
    int best = 0;
#pragma unroll 1
    for (int k = 0; k < K; k += 4) {
        const float* e0 = E + k * C;
        float a0 = 0.0f, a1 = 0.0f, a2 = 0.0f, a3 = 0.0f;
#pragma unroll
        for (int c = 0; c < C; ++c) {
            float zc = z[c];
            a0 = __builtin_fmaf(zc, e0[c], a0);
            a1 = __builtin_fmaf(zc, e0[C + c], a1);
            a2 = __builtin_fmaf(zc, e0[2 * C + c], a2);
            a3 = __builtin_fmaf(zc, e0[3 * C + c], a3);
        }
        float A0 = zn + ek[k],     A1 = zn + ek[k + 1];
        float A2 = zn + ek[k + 2], A3 = zn + ek[k + 3];
        float d0 = A0 - 2.0f * a0, d1 = A1 - 2.0f * a1;
        float d2 = A2 - 2.0f * a2, d3 = A3 - 2.0f * a3;
        if (d0 < dmin) { dmin = d0; best = k; }
        if (d1 < dmin) { dmin = d1; best = k + 1; }
        if (d2 < dmin) { dmin = d2; best = k + 2; }
        if (d3 < dmin) { dmin = d3; best = k + 3; }
    }
    const float4* eb4 = (const float4*)(E + best * C);
    float* o0 = out + b * (C * HW) + hw;
    float ls = 0.0f;
#pragma unroll
    for (int c4 = 0; c4 < 16; ++c4) {
        float4 e4 = eb4[c4];
        int cb = c4 * 4;
        float f0 = e4.x - z[cb + 0]; o0[(cb + 0) * HW] = z[cb + 0] + f0; ls += f0 * f0;
        float f1 = e4.y - z[cb + 1]; o0[(cb + 1) * HW] = z[cb + 1] + f1; ls += f1 * f1;
        float f2 = e4.z - z[cb + 2]; o0[(cb + 2) * HW] = z[cb + 2] + f2; ls += f2 * f2;
        float f3 = e4.w - z[cb + 3]; o0[(cb + 3) * HW] = z[cb + 3] + f3; ls += f3 * f3;
    }
    out[OUT0 + n] = (float)best;
#pragma unroll
    for (int off = 32; off > 0; off >>= 1) ls += __shfl_xor(ls, off, 64);
    if ((threadIdx.x & 63) == 0) partials[n >> 6] = ls;
}

__global__ __launch_bounds__(256) void loss_kernel(const float* __restrict__ partials,
                                                   float* __restrict__ out) {
    __shared__ double sm[256];
    int t = threadIdx.x;
    double s = 0.0;
    for (int i = t; i < (N_TOTAL / 64); i += 256) s += (double)partials[i];
    sm[t] = s;
    __syncthreads();
    for (int o = 128; o > 0; o >>= 1) {
        if (t < o) sm[t] += sm[t + o];
        __syncthreads();
    }
    if (t == 0) {
        float m = (float)(sm[0] * (1.0 / 8388608.0));
        out[OUT0 + N_TOTAL] = m + 0.25f * m;
    }
}

extern "C" void kernel_launch(void* const* d_in, const int* in_sizes, int n_in,
                              void* d_out, int out_size, void* d_ws, size_t ws_size,
                              hipStream_t stream) {
    const float* Z = (const float*)d_in[0];
    const float* E = (const float*)d_in[1];
    float* out = (float*)d_out;
    float* ws = (float*)d_ws;
    float* ek = ws + WS_EK;

    if (ws_size >= (size_t)WS_NEED2 * sizeof(float)) {
        int* besti   = (int*)(ws + WS_BESTI);
        int* ulistB  = (int*)(ws + WS_ULISTB);
        int* ucnt    = (int*)(ws + WS_UCNT);
        int* bflag   = (int*)(ws + WS_BFLAG);
        short* EbfS  = (short*)(ws + WS_EBF);
        float* Etg   = ws + WS_ETG;
        float* rowloss = ws + WS_ROWLOSS;

        hipLaunchKernelGGL(eprep2, dim3(K / 256), dim3(256), 0, stream,
                           E, ek, EbfS, Etg, ucnt);
        hipLaunchKernelGGL(vq_mfma, dim3(N_TOTAL / MT), dim3(256), 0, stream,
                           Z, E, ek, EbfS, besti, ulistB, ucnt, bflag);
        hipLaunchKernelGGL(vq_exact_block, dim3(N_TOTAL / MT), dim3(256), 0, stream,
                           Z, Etg, ek, bflag, besti);
        hipLaunchKernelGGL(vq_fb_gap, dim3(2048), dim3(256), 0, stream,
                           Z, Etg, ek, ulistB, ucnt, besti);
        hipLaunchKernelGGL(vq_epilogue2, dim3(N_TOTAL / 256), dim3(256), 0, stream,
                           Z, E, besti, out, rowloss);
        hipLaunchKernelGGL(loss2, dim3(1), dim3(256), 0, stream, rowloss, out);
    } else {
        float* partials = ws + 1024;
        hipLaunchKernelGGL(ek_kernel, dim3(4), dim3(256), 0, stream, E, ek);
        hipLaunchKernelGGL(vq_combined, dim3(N_TOTAL / 256), dim3(256), 0, stream,
                           Z, E, ek, out, partials);
        hipLaunchKernelGGL(loss_kernel, dim3(1), dim3(256), 0, stream, partials, out);
    }
}

// Round 16
// 219.888 us; speedup vs baseline: 3.4269x; 2.1525x over previous
//
#include <hip/hip_runtime.h>

#define C 64
#define K 1024
#define HW 4096
#define N_TOTAL 131072   // 32*64*64
#define OUT0 8388608     // 32*64*64*64 (z_q_out elements)
#define MT 128           // n-rows per block
#define KT 128           // codes per K-tile
#define NTILES (K / KT)

// d_ws float layout
#define WS_EK        0
#define WS_PARTIALS  1024
#define WS_ETG       3072                 // 64*1024 floats
#define WS_NEED_FLOATS (3072 + C * K)

typedef unsigned int u32;
typedef unsigned long long u64;
typedef const __attribute__((address_space(1))) void* gas_ptr;
typedef __attribute__((address_space(3))) void* las_ptr;

// monotone float map + index pack: lexicographic min == (min d, then min k)
__device__ __forceinline__ u64 packdk(float d, int k) {
    u32 b = __float_as_uint(d);
    u32 m = b ^ ((u32)((int)b >> 31) | 0x80000000u);
    return ((u64)m << 32) | (u32)k;
}

// ---------------------------------------------------------------------------
// Kernel 1 (main path): E prep. ek = ||e_k||^2 numpy pairwise-8 (FROZEN) +
// transpose E into Etg[c][k] so vq_main's DMA staging is row-linear (the
// exact contiguous pattern global_load_lds requires).
// ---------------------------------------------------------------------------
__global__ __launch_bounds__(256) void eprep_kernel(const float* __restrict__ E,
                                                    float* __restrict__ Etg,
                                                    float* __restrict__ ek) {
#pragma clang fp contract(off)
    int k = blockIdx.x * 256 + threadIdx.x;
    const float* e = E + k * C;
    float ev[C];
#pragma unroll
    for (int c4 = 0; c4 < 16; ++c4) {
        float4 v = *(const float4*)(e + c4 * 4);
        ev[c4 * 4 + 0] = v.x; ev[c4 * 4 + 1] = v.y;
        ev[c4 * 4 + 2] = v.z; ev[c4 * 4 + 3] = v.w;
    }
    float r[8];
#pragma unroll
    for (int j = 0; j < 8; ++j) r[j] = ev[j] * ev[j];
#pragma unroll
    for (int i = 8; i < C; i += 8)
#pragma unroll
        for (int j = 0; j < 8; ++j) r[j] += ev[i + j] * ev[i + j];
    ek[k] = ((r[0] + r[1]) + (r[2] + r[3])) + ((r[4] + r[5]) + (r[6] + r[7]));
#pragma unroll
    for (int c = 0; c < C; ++c) Etg[c * K + k] = ev[c];   // coalesced per c
}

// ---------------------------------------------------------------------------
// Kernel 2 (main path): register-blocked VALU GEMM argmin + fused epilogue.
// THE SESSION'S BEST-MEASURED KERNEL (Round-9 bench: 219.95 us total).
// Structure: 8x8 per-thread tile (1.0 LDS-byte/fma), Zt fp32 in LDS (32KB),
// E-tile staged via __builtin_amdgcn_global_load_lds (zero staging VGPRs,
// no ds_writes; avoids the R5/R6/R8 allocator collapse), single-buffered
// EtS (32KB), 68KB LDS -> 2 blocks/CU.
// Per tile: compute(8K cyc) -> barrier -> 8 DMA issues/wave -> barrier.
// Numerics FROZEN (absmax 0.0 R1-R10): sequential fma c=0..63 per (n,k);
// d = fmaf(-2,acc,fl(zn+ek)) (2a exact); ascending-k strict <; R4-verified
// lane mapping, k-decode, u64 lexicographic reduce; frozen zn/epilogue/loss.
// ---------------------------------------------------------------------------
__global__ __launch_bounds__(256, 2) void vq_main(const float* __restrict__ Z,
                                                  const float* __restrict__ E,
                                                  const float* __restrict__ Etg,
                                                  const float* __restrict__ ek,
                                                  float* __restrict__ out,
                                                  float* __restrict__ partials) {
#pragma clang fp contract(off)
    __shared__ float Zt[C * MT];     // [c][n_local]  32 KB
    __shared__ float EtS[C * KT];    // [c][k_local]  32 KB
    __shared__ float znbuf[MT];
    __shared__ u64 red[4][8][8];     // [wave][i_l][m]

    const int t = threadIdx.x;
    const int wave = t >> 6, lane = t & 63;
    const int n0 = blockIdx.x * MT;
    const int b = n0 >> 12;
    const int hw0 = n0 & 4095;
    const float* zbase = Z + b * (C * HW) + hw0;

    // ---- stage Zt (coalesced; Z is already [c][n]-contiguous) ------------
#pragma unroll
    for (int r = 0; r < 8; ++r) {
        int idx4 = r * 256 + t;
        int c = idx4 >> 5, n4 = idx4 & 31;
        float4 v = *(const float4*)(zbase + c * HW + n4 * 4);
        *(float4*)(&Zt[c * MT + n4 * 4]) = v;
    }
    // ---- stage EtS tile 0 via DMA: issue q = wave*8+p covers EtS rows
    // {2q,2q+1} (1KB). LDS base uniform per wave-issue; HW dest =
    // base + lane*16B which matches row-linear layout exactly. ------------
#pragma unroll
    for (int p = 0; p < 8; ++p) {
        int q = wave * 8 + p;
        int c = 2 * q + (lane >> 5);
        const float* gsrc = Etg + c * K + (lane & 31) * 4;
        __builtin_amdgcn_global_load_lds((gas_ptr)gsrc, (las_ptr)&EtS[q * 256],
                                         16, 0, 0);
    }
    __syncthreads();   // drains vmcnt: Zt and EtS tile0 ready

    // ---- zn per row (numpy pairwise-8 order, FROZEN) ----
    if (t < MT) {
        float r8[8];
#pragma unroll
        for (int j = 0; j < 8; ++j) { float v = Zt[j * MT + t]; r8[j] = v * v; }
#pragma unroll
        for (int i = 1; i < 8; ++i)
#pragma unroll
            for (int j = 0; j < 8; ++j) { float v = Zt[(i * 8 + j) * MT + t]; r8[j] += v * v; }
        znbuf[t] = ((r8[0] + r8[1]) + (r8[2] + r8[3])) + ((r8[4] + r8[5]) + (r8[6] + r8[7]));
    }
    __syncthreads();

    const int i_l = lane & 7, j_l = lane >> 3;
    const int ig = ((wave & 1) << 3) | i_l;    // n-group 0..15 (rows ig*8..+8)
    const int jg = ((wave >> 1) << 3) | j_l;   // k-group 0..15 (codes jg*8..+8)

    float znm[8];
#pragma unroll
    for (int m = 0; m < 8; ++m) znm[m] = znbuf[ig * 8 + m];

    float dmin[8];
    int qb[8];
#pragma unroll
    for (int m = 0; m < 8; ++m) { dmin[m] = __builtin_inff(); qb[m] = 0; }

#pragma unroll 1
    for (int tile = 0; tile < NTILES; ++tile) {
        float ekq[8];
        {
            const float* ekp = ek + tile * KT + jg * 8;
            float4 a = *(const float4*)ekp;
            float4 bq = *(const float4*)(ekp + 4);
            ekq[0] = a.x;  ekq[1] = a.y;  ekq[2] = a.z;  ekq[3] = a.w;
            ekq[4] = bq.x; ekq[5] = bq.y; ekq[6] = bq.z; ekq[7] = bq.w;
        }

        float acc[8][8];
#pragma unroll
        for (int m = 0; m < 8; ++m)
#pragma unroll
            for (int q = 0; q < 8; ++q) acc[m][q] = 0.0f;

#pragma unroll 4
        for (int c = 0; c < C; ++c) {
            float4 za = *(const float4*)(&Zt[c * MT + ig * 8]);
            float4 zb = *(const float4*)(&Zt[c * MT + ig * 8 + 4]);
            float4 ea = *(const float4*)(&EtS[c * KT + jg * 8]);
            float4 eb = *(const float4*)(&EtS[c * KT + jg * 8 + 4]);
            float zm[8] = {za.x, za.y, za.z, za.w, zb.x, zb.y, zb.z, zb.w};
            float eq[8] = {ea.x, ea.y, ea.z, ea.w, eb.x, eb.y, eb.z, eb.w};
#pragma unroll
            for (int m = 0; m < 8; ++m)
#pragma unroll
                for (int q = 0; q < 8; ++q)
                    acc[m][q] = __builtin_fmaf(zm[m], eq[q], acc[m][q]);
        }

        const int qbase = tile * 8;
#pragma unroll
        for (int m = 0; m < 8; ++m)
#pragma unroll
            for (int q = 0; q < 8; ++q) {
                float A = znm[m] + ekq[q];                     // fl(zn+ek)
                float d = __builtin_fmaf(-2.0f, acc[m][q], A); // == fl(A-2a), 2a exact
                if (d < dmin[m]) { dmin[m] = d; qb[m] = qbase + q; }
            }

        __syncthreads();   // all waves done READING EtS
        if (tile + 1 < NTILES) {
            const float* src = Etg + (tile + 1) * KT;
#pragma unroll
            for (int p = 0; p < 8; ++p) {
                int q = wave * 8 + p;
                int c = 2 * q + (lane >> 5);
                const float* gsrc = src + c * K + (lane & 31) * 4;
                __builtin_amdgcn_global_load_lds((gas_ptr)gsrc,
                                                 (las_ptr)&EtS[q * 256],
                                                 16, 0, 0);
            }
        }
        __syncthreads();   // vmcnt(0) drain before barrier -> EtS ready
    }

    // decode per-thread k, pack to (mono(d),k), reduce (R4-verified path)
    u64 bestp[8];
#pragma unroll
    for (int m = 0; m < 8; ++m) {
        int q8 = qb[m];
        int k = ((q8 >> 3) << 7) + jg * 8 + (q8 & 7);
        bestp[m] = packdk(dmin[m], k);
    }
#pragma unroll
    for (int m = 0; m < 8; ++m) {
        u64 v = bestp[m];
#pragma unroll
        for (int mask = 8; mask <= 32; mask <<= 1) {
            u64 o = __shfl_xor(v, mask, 64);
            v = o < v ? o : v;
        }
        bestp[m] = v;
    }
    if (j_l == 0) {
#pragma unroll
        for (int m = 0; m < 8; ++m) red[wave][i_l][m] = bestp[m];
    }
    __syncthreads();

    // ---- fused epilogue: thread t<128 owns row t (FROZEN body/order) ----
    if (t < MT) {
        int igg = t >> 3, m = t & 7;
        int ihalf = igg >> 3, iw = igg & 7;   // waves {ihalf, ihalf+2} hold it
        u64 a = red[ihalf][iw][m];
        u64 b2 = red[ihalf + 2][iw][m];
        u64 v = b2 < a ? b2 : a;
        int best = (int)(v & 0xFFFFFFFFu);
        int n = n0 + t;
        out[OUT0 + n] = (float)best;

        const float4* eb4 = (const float4*)(E + best * C);
        float* o0 = out + b * (C * HW) + hw0 + t;
        float ls = 0.0f;
#pragma unroll
        for (int c4 = 0; c4 < 16; ++c4) {
            float4 e4 = eb4[c4];
            int cb = c4 * 4;
            float z0 = Zt[(cb + 0) * MT + t], z1 = Zt[(cb + 1) * MT + t];
            float z2 = Zt[(cb + 2) * MT + t], z3 = Zt[(cb + 3) * MT + t];
            float f0 = e4.x - z0; o0[(cb + 0) * HW] = z0 + f0; ls += f0 * f0;
            float f1 = e4.y - z1; o0[(cb + 1) * HW] = z1 + f1; ls += f1 * f1;
            float f2 = e4.z - z2; o0[(cb + 2) * HW] = z2 + f2; ls += f2 * f2;
            float f3 = e4.w - z3; o0[(cb + 3) * HW] = z3 + f3; ls += f3 * f3;
        }
#pragma unroll
        for (int off = 32; off > 0; off >>= 1) ls += __shfl_xor(ls, off, 64);
        if ((t & 63) == 0) partials[n >> 6] = ls;
    }
}

// ---------------------------------------------------------------------------
// Fallback path kernels (tiny ws): R2/R4 structure, FROZEN.
// ---------------------------------------------------------------------------
__global__ __launch_bounds__(256) void ek_kernel(const float* __restrict__ E,
                                                 float* __restrict__ ek) {
#pragma clang fp contract(off)
    int k = blockIdx.x * 256 + threadIdx.x;
    if (k >= K) return;
    const float* e = E + k * C;
    float r[8];
#pragma unroll
    for (int j = 0; j < 8; ++j) { float v = e[j]; r[j] = v * v; }
#pragma unroll
    for (int i = 8; i < C; i += 8) {
#pragma unroll
        for (int j = 0; j < 8; ++j) { float v = e[i + j]; r[j] += v * v; }
    }
    ek[k] = ((r[0] + r[1]) + (r[2] + r[3])) + ((r[4] + r[5]) + (r[6] + r[7]));
}

__global__ __launch_bounds__(256, 4) void vq_combined(const float* __restrict__ Z,
                                                      const float* __restrict__ E,
                                                      const float* __restrict__ ek,
                                                      float* __restrict__ out,
                                                      float* __restrict__ partials) {
#pragma clang fp contract(off)
    int n = blockIdx.x * 256 + threadIdx.x;
    int b = n >> 12;
    int hw = n & 4095;
    const float* zp = Z + b * (C * HW) + hw;

    float z[C];
#pragma unroll
    for (int c = 0; c < C; ++c) z[c] = zp[c * HW];
    float zn;
    {
        float r[8];
#pragma unroll
        for (int j = 0; j < 8; ++j) r[j] = z[j] * z[j];
#pragma unroll
        for (int i = 8; i < C; i += 8) {
#pragma unroll
            for (int j = 0; j < 8; ++j) r[j] += z[i + j] * z[i + j];
        }
        zn = ((r[0] + r[1]) + (r[2] + r[3])) + ((r[4] + r[5]) + (r[6] + r[7]));
    }

    float dmin = __builtin_inff();
    int best = 0;
#pragma unroll 1
    for (int k = 0; k < K; k += 4) {
        const float* e0 = E + k * C;
        float a0 = 0.0f, a1 = 0.0f, a2 = 0.0f, a3 = 0.0f;
#pragma unroll
        for (int c = 0; c < C; ++c) {
            float zc = z[c];
            a0 = __builtin_fmaf(zc, e0[c], a0);
            a1 = __builtin_fmaf(zc, e0[C + c], a1);
            a2 = __builtin_fmaf(zc, e0[2 * C + c], a2);
            a3 = __builtin_fmaf(zc, e0[3 * C + c], a3);
        }
        float A0 = zn + ek[k],     A1 = zn + ek[k + 1];
        float A2 = zn + ek[k + 2], A3 = zn + ek[k + 3];
        float d0 = A0 - 2.0f * a0, d1 = A1 - 2.0f * a1;
        float d2 = A2 - 2.0f * a2, d3 = A3 - 2.0f * a3;
        if (d0 < dmin) { dmin = d0; best = k; }
        if (d1 < dmin) { dmin = d1; best = k + 1; }
        if (d2 < dmin) { dmin = d2; best = k + 2; }
        if (d3 < dmin) { dmin = d3; best = k + 3; }
    }

    const float4* eb4 = (const float4*)(E + best * C);
    float* o0 = out + b * (C * HW) + hw;
    float ls = 0.0f;
#pragma unroll
    for (int c4 = 0; c4 < 16; ++c4) {
        float4 e4 = eb4[c4];
        int cb = c4 * 4;
        float f0 = e4.x - z[cb + 0]; o0[(cb + 0) * HW] = z[cb + 0] + f0; ls += f0 * f0;
        float f1 = e4.y - z[cb + 1]; o0[(cb + 1) * HW] = z[cb + 1] + f1; ls += f1 * f1;
        float f2 = e4.z - z[cb + 2]; o0[(cb + 2) * HW] = z[cb + 2] + f2; ls += f2 * f2;
        float f3 = e4.w - z[cb + 3]; o0[(cb + 3) * HW] = z[cb + 3] + f3; ls += f3 * f3;
    }
    out[OUT0 + n] = (float)best;
#pragma unroll
    for (int off = 32; off > 0; off >>= 1) ls += __shfl_xor(ls, off, 64);
    if ((threadIdx.x & 63) == 0) partials[n >> 6] = ls;
}

// ---------------------------------------------------------------------------
// Final loss reduction in fp64 (FROZEN).
// ---------------------------------------------------------------------------
__global__ __launch_bounds__(256) void loss_kernel(const float* __restrict__ partials,
                                                   float* __restrict__ out) {
    __shared__ double sm[256];
    int t = threadIdx.x;
    double s = 0.0;
    for (int i = t; i < (N_TOTAL / 64); i += 256) s += (double)partials[i];
    sm[t] = s;
    __syncthreads();
    for (int o = 128; o > 0; o >>= 1) {
        if (t < o) sm[t] += sm[t + o];
        __syncthreads();
    }
    if (t == 0) {
        float m = (float)(sm[0] * (1.0 / 8388608.0));
        float loss = m + 0.25f * m;
        out[OUT0 + N_TOTAL] = loss;
    }
}

extern "C" void kernel_launch(void* const* d_in, const int* in_sizes, int n_in,
                              void* d_out, int out_size, void* d_ws, size_t ws_size,
                              hipStream_t stream) {
    const float* Z = (const float*)d_in[0];
    const float* E = (const float*)d_in[1];
    float* out = (float*)d_out;
    float* ws = (float*)d_ws;
    float* ek = ws + WS_EK;
    float* partials = ws + WS_PARTIALS;

    if (ws_size >= (size_t)WS_NEED_FLOATS * sizeof(float)) {
        float* Etg = ws + WS_ETG;
        hipLaunchKernelGGL(eprep_kernel, dim3(K / 256), dim3(256), 0, stream,
                           E, Etg, ek);
        hipLaunchKernelGGL(vq_main, dim3(N_TOTAL / MT), dim3(256), 0, stream,
                           Z, E, Etg, ek, out, partials);
    } else {
        hipLaunchKernelGGL(ek_kernel, dim3(4), dim3(256), 0, stream, E, ek);
        hipLaunchKernelGGL(vq_combined, dim3(N_TOTAL / 256), dim3(256), 0, stream,
                           Z, E, ek, out, partials);
    }
    hipLaunchKernelGGL(loss_kernel, dim3(1), dim3(256), 0, stream, partials, out);
}